// Round 1
// 1652.527 us; speedup vs baseline: 1.1498x; 1.1498x over previous
//
#include <hip/hip_runtime.h>

// GCLSDA encoder: ego=concat(U,I); 3x { ego = A@ego; ego += sign(ego)*nhat*0.1; acc+=ego }
// Outputs: final=acc/3, cl=ego_layer1.
// Numerics: SpMM accumulates per (row,dim) sequentially in ascending edge-index
// order with separate _rn mul/add (matches np.add.at); norm uses numpy
// pairwise-sum 8-accumulator pattern. This exact order passed round 1
// (absmax 1.22e-4) — the CSR build below reproduces the IDENTICAL cv order.
//
// CSR build v3: bucket = row>>8 (782 buckets).
//  A1 k_bcount : per-bucket edge counts, LDS-aggregated.
//  k_scan782   : exclusive scan -> bbase, gcur; rs[N]=E.
//  A2 k_bin    : append {col,val,key} to bucket region (sequential frontiers,
//                compact HBM writes vs random 4B scatter).
//  B  k_build  : one WG per bucket. v3 REWRITE (was 530us / 667MB writes from
//                a per-row insertion sort shuffling cv in GLOBAL memory):
//                keys are unique ((rl<<24)|e), so final slot = start[rl] +
//                rank, rank = #{same-row keys < mine}. LDS histogram -> scan
//                -> LDS key scatter -> parallel dependency-free LDS rank scan
//                -> write each cv entry EXACTLY ONCE. Same final order as the
//                verified insertion sort (rank over (rl,e) == ascending e per
//                row), ~13x less global traffic, no divergent serial chains.
//                KEY RECOVERY MUST BE LOGICAL SHIFT: (unsigned)key>>24
//                (signed >> sign-extends for row-local >=128 -> OOB crash, R2).
//                Same-row signed key compare is safe: same top byte.

#define USER_NUM 100000
#define N_NODES  200000
#define EMB      64
#define N_EDGES  6400000
#define NBUCK    782        // ceil(200000/256)
#define CAP      9216       // max edges/bucket on LDS fast path (mu=8192, +11 sigma)
#define EPB      4096       // edges per block in A1/A2

static constexpr size_t BUFA_OFF  = 0;
static constexpr size_t BUFB_OFF  = 51200000;
static constexpr size_t CV_OFF    = 102400000;
static constexpr size_t RS_OFF    = 153600000;
static constexpr size_t SMALL_OFF = 154400016;
static constexpr size_t NRM_OFF   = 155200016;
static constexpr size_t WS_NEED   = 156000016;

// ---- Pass A1: bucket counts ----
__global__ void k_bcount(const int* __restrict__ rows, int* __restrict__ bcnt) {
    __shared__ int h[NBUCK];
    for (int i = threadIdx.x; i < NBUCK; i += 256) h[i] = 0;
    __syncthreads();
    int base = blockIdx.x * EPB;
    for (int k = 0; k < EPB / 256; ++k) {
        int e = base + k * 256 + threadIdx.x;
        if (e < N_EDGES) atomicAdd(&h[rows[e] >> 8], 1);
    }
    __syncthreads();
    for (int i = threadIdx.x; i < NBUCK; i += 256) {
        int c = h[i];
        if (c) atomicAdd(&bcnt[i], c);
    }
}

// ---- scan of 782 bucket counts -> bbase (exclusive), gcur; rs[N]=E ----
__global__ void k_scan782(const int* __restrict__ bcnt, int* __restrict__ bbase,
                          int* __restrict__ gcur, int* __restrict__ rs) {
    __shared__ int s[1024];
    int i = threadIdx.x;
    int v = (i < NBUCK) ? bcnt[i] : 0;
    s[i] = v;
    __syncthreads();
    for (int off = 1; off < 1024; off <<= 1) {
        int t = 0;
        if (i >= off) t = s[i - off];
        __syncthreads();
        s[i] += t;
        __syncthreads();
    }
    if (i < NBUCK) {
        int ex = s[i] - v;
        bbase[i] = ex;
        gcur[i] = ex;
    }
    if (i == 0) rs[N_NODES] = N_EDGES;
}

// ---- Pass A2: bin edges into bucket regions ----
__global__ void k_bin(const int* __restrict__ rows, const int* __restrict__ cols,
                      const float* __restrict__ vals, int* __restrict__ gcur,
                      int4* __restrict__ bins) {
    __shared__ int h[NBUCK];
    __shared__ int gb[NBUCK];
    for (int i = threadIdx.x; i < NBUCK; i += 256) h[i] = 0;
    __syncthreads();
    int base = blockIdx.x * EPB;
    int myr[EPB / 256];
    int myrank[EPB / 256];
    for (int k = 0; k < EPB / 256; ++k) {
        int e = base + k * 256 + threadIdx.x;
        myr[k] = -1;
        if (e < N_EDGES) {
            int r = rows[e];
            myr[k] = r;
            myrank[k] = atomicAdd(&h[r >> 8], 1);
        }
    }
    __syncthreads();
    for (int i = threadIdx.x; i < NBUCK; i += 256) {
        int c = h[i];
        if (c) gb[i] = atomicAdd(&gcur[i], c);
    }
    __syncthreads();
    for (int k = 0; k < EPB / 256; ++k) {
        int e = base + k * 256 + threadIdx.x;
        int r = myr[k];
        if (r >= 0) {
            int b = r >> 8;
            int pos = gb[b] + myrank[k];
            int key = ((r & 255) << 24) | e;   // e < 2^23, row-local in top byte
            bins[pos] = make_int4(cols[e], __float_as_int(vals[e]), key, 0);
        }
    }
}

// ---- Pass B: per-bucket row-grouping + stable (edge-idx) ordering -> cv, rs ----
__global__ __launch_bounds__(256) void k_build(int4* __restrict__ bins,
                                               const int* __restrict__ bcnt,
                                               const int* __restrict__ bbase,
                                               int2* __restrict__ cv,
                                               int* __restrict__ rs) {
    __shared__ int cnt[256];
    __shared__ int start[256];
    __shared__ int cur[256];
    __shared__ int scanbuf[256];
    __shared__ int eKey[CAP];     // grouped keys (fast path)
    __shared__ short idxS[CAP];   // grouped -> bins-local index (fast path)
    int tid = threadIdx.x;
    int b = blockIdx.x;
    int n = bcnt[b];
    int base = bbase[b];
    int rowbase = b << 8;
    cnt[tid] = 0;
    __syncthreads();
    // step 1: per-row-local histogram (LOGICAL shift: rl in [0,255])
    for (int i = tid; i < n; i += 256) {
        unsigned key = (unsigned)bins[base + i].z;
        atomicAdd(&cnt[key >> 24], 1);
    }
    __syncthreads();
    // exclusive scan of cnt -> start
    int v = cnt[tid];
    scanbuf[tid] = v;
    __syncthreads();
    for (int off = 1; off < 256; off <<= 1) {
        int t = 0;
        if (tid >= off) t = scanbuf[tid - off];
        __syncthreads();
        scanbuf[tid] += t;
        __syncthreads();
    }
    start[tid] = scanbuf[tid] - v;
    {
        int row = rowbase + tid;
        if (row < N_NODES) rs[row] = base + start[tid];
    }
    cur[tid] = 0;
    __syncthreads();
    if (n <= CAP) {
        // step 2: group keys by row into LDS (intra-row order arbitrary here)
        for (int i = tid; i < n; i += 256) {
            int key = bins[base + i].z;                 // L2-hot re-read
            int rl = (int)((unsigned)key >> 24);
            int p = start[rl] + atomicAdd(&cur[rl], 1);
            eKey[p] = key;
            idxS[p] = (short)i;
        }
        __syncthreads();
        // step 3: rank = #{same-row keys < mine} -> final slot; write cv ONCE.
        // Keys unique (distinct e) => bijection. Same top byte within a row
        // => signed compare orders by edge idx. Independent LDS reads, no
        // dependency chain, no divergent while-loops, no global shuffling.
        for (int p = tid; p < n; p += 256) {
            int k = eKey[p];
            int rl = (int)((unsigned)k >> 24);
            int s0 = start[rl];
            int s1 = s0 + cnt[rl];
            int rank = 0;
            int q = s0;
            for (; q + 4 <= s1; q += 4) {
                rank += (eKey[q]     < k);
                rank += (eKey[q + 1] < k);
                rank += (eKey[q + 2] < k);
                rank += (eKey[q + 3] < k);
            }
            for (; q < s1; ++q) rank += (eKey[q] < k);
            int4 e4 = bins[base + (int)idxS[p]];        // random within 147KB, L2-hot
            cv[base + s0 + rank] = make_int2(e4.x, e4.y);
        }
    } else {
        // overflow fallback (statistically unreachable, +11 sigma): keys in
        // bins[].w, global insertion sort (slow but correct for any input).
        for (int i = tid; i < n; i += 256) {
            int4 e4 = bins[base + i];
            int rl = (int)((unsigned)e4.z >> 24);
            int p = start[rl] + atomicAdd(&cur[rl], 1);
            cv[base + p] = make_int2(e4.x, e4.y);
            bins[base + p].w = e4.z;
        }
        __syncthreads();
        int c = cnt[tid];
        if (c > 1) {
            int s0 = start[tid];
            int s1 = s0 + c;
            for (int i = s0 + 1; i < s1; ++i) {
                int ke = bins[base + i].w;
                int2 kv = cv[base + i];
                int j = i - 1;
                while (j >= s0 && bins[base + j].w > ke) {
                    bins[base + j + 1].w = bins[base + j].w;
                    cv[base + j + 1] = cv[base + j];
                    --j;
                }
                bins[base + j + 1].w = ke;
                cv[base + j + 1] = kv;
            }
        }
    }
}

// ---- SpMM: one thread per (row, 4-dim group); ascending-edge sequential adds ----
__global__ void k_spmm(const int* __restrict__ rs, const int2* __restrict__ cv,
                       const float* __restrict__ x, float* __restrict__ y) {
    int t = blockIdx.x * blockDim.x + threadIdx.x;
    if (t >= N_NODES * 16) return;
    int r = t >> 4;
    int c = (t & 15) << 2;
    int j0 = rs[r], j1 = rs[r + 1];
    float a0 = 0.f, a1 = 0.f, a2 = 0.f, a3 = 0.f;
    if (j0 < j1) {
        int2 cvc = cv[j0];
        float4 xv = *(const float4*)(x + cvc.x * EMB + c);
        for (int j = j0; j < j1; ++j) {
            int2 cvn = cvc;
            float4 xn = xv;
            if (j + 1 < j1) {
                cvn = cv[j + 1];
                xn = *(const float4*)(x + cvn.x * EMB + c);
            }
            float v = __int_as_float(cvc.y);
            a0 = __fadd_rn(a0, __fmul_rn(v, xv.x));
            a1 = __fadd_rn(a1, __fmul_rn(v, xv.y));
            a2 = __fadd_rn(a2, __fmul_rn(v, xv.z));
            a3 = __fadd_rn(a3, __fmul_rn(v, xv.w));
            cvc = cvn;
            xv = xn;
        }
    }
    *(float4*)(y + r * EMB + c) = make_float4(a0, a1, a2, a3);
}

// ---- per-row L2 norm of noise, numpy pairwise order (8 accumulators, n=64) ----
__global__ void k_norm(const float* __restrict__ nk, float* __restrict__ nrm) {
    __shared__ float tile[2][64 * 65];
    int wave = threadIdx.x >> 6;
    int lane = threadIdx.x & 63;
    int base = blockIdx.x * 128 + wave * 64;
    for (int rr = 0; rr < 64; ++rr) {
        int row = base + rr;
        float v = 0.f;
        if (row < N_NODES) v = nk[row * EMB + lane];
        tile[wave][rr * 65 + lane] = v;
    }
    __syncthreads();
    int row = base + lane;
    if (row < N_NODES) {
        const float* tp = &tile[wave][lane * 65];
        float rj[8];
        #pragma unroll
        for (int j = 0; j < 8; ++j) {
            float xj = tp[j];
            rj[j] = __fmul_rn(xj, xj);
        }
        #pragma unroll
        for (int i = 8; i < 64; i += 8) {
            #pragma unroll
            for (int j = 0; j < 8; ++j) {
                float xj = tp[i + j];
                rj[j] = __fadd_rn(rj[j], __fmul_rn(xj, xj));
            }
        }
        float s01 = __fadd_rn(rj[0], rj[1]);
        float s23 = __fadd_rn(rj[2], rj[3]);
        float s45 = __fadd_rn(rj[4], rj[5]);
        float s67 = __fadd_rn(rj[6], rj[7]);
        float ss = __fadd_rn(__fadd_rn(s01, s23), __fadd_rn(s45, s67));
        float nv = __fsqrt_rn(ss);
        nv = fmaxf(nv, 1e-12f);
        nrm[row] = nv;
    }
}

// ---- epilogue: perturb, acc update, cl capture ----
__global__ void k_epi(float* __restrict__ ego, const float* __restrict__ nk,
                      const float* __restrict__ nrm, float* __restrict__ accF,
                      float* __restrict__ clF, int mode) {
    int t = blockIdx.x * blockDim.x + threadIdx.x;
    if (t >= N_NODES * 16) return;
    int r = t >> 4;
    int idx = t << 2;
    float4 y4 = *(float4*)(ego + idx);
    float4 n4 = *(const float4*)(nk + idx);
    float nv = nrm[r];
    float4 e4;
    {
        float s, q;
        s = (y4.x > 0.f) ? 1.f : ((y4.x < 0.f) ? -1.f : 0.f);
        q = __fdiv_rn(n4.x, nv);
        e4.x = __fadd_rn(y4.x, __fmul_rn(__fmul_rn(s, q), 0.1f));
        s = (y4.y > 0.f) ? 1.f : ((y4.y < 0.f) ? -1.f : 0.f);
        q = __fdiv_rn(n4.y, nv);
        e4.y = __fadd_rn(y4.y, __fmul_rn(__fmul_rn(s, q), 0.1f));
        s = (y4.z > 0.f) ? 1.f : ((y4.z < 0.f) ? -1.f : 0.f);
        q = __fdiv_rn(n4.z, nv);
        e4.z = __fadd_rn(y4.z, __fmul_rn(__fmul_rn(s, q), 0.1f));
        s = (y4.w > 0.f) ? 1.f : ((y4.w < 0.f) ? -1.f : 0.f);
        q = __fdiv_rn(n4.w, nv);
        e4.w = __fadd_rn(y4.w, __fmul_rn(__fmul_rn(s, q), 0.1f));
    }
    *(float4*)(ego + idx) = e4;
    if (mode == 0) {
        *(float4*)(accF + idx) = e4;
        *(float4*)(clF + idx) = e4;
    } else if (mode == 1) {
        float4 a = *(float4*)(accF + idx);
        a.x = __fadd_rn(a.x, e4.x);
        a.y = __fadd_rn(a.y, e4.y);
        a.z = __fadd_rn(a.z, e4.z);
        a.w = __fadd_rn(a.w, e4.w);
        *(float4*)(accF + idx) = a;
    } else {
        float4 a = *(float4*)(accF + idx);
        float4 f;
        f.x = __fdiv_rn(__fadd_rn(a.x, e4.x), 3.0f);
        f.y = __fdiv_rn(__fadd_rn(a.y, e4.y), 3.0f);
        f.z = __fdiv_rn(__fadd_rn(a.z, e4.z), 3.0f);
        f.w = __fdiv_rn(__fadd_rn(a.w, e4.w), 3.0f);
        *(float4*)(accF + idx) = f;
    }
}

extern "C" void kernel_launch(void* const* d_in, const int* in_sizes, int n_in,
                              void* d_out, int out_size, void* d_ws, size_t ws_size,
                              hipStream_t stream) {
    if (ws_size < WS_NEED) return;

    const float* user_emb = (const float*)d_in[0];
    const float* item_emb = (const float*)d_in[1];
    const int*   adj_rows = (const int*)d_in[2];
    const int*   adj_cols = (const int*)d_in[3];
    const float* adj_vals = (const float*)d_in[4];
    const float* noise    = (const float*)d_in[5];

    char* ws = (char*)d_ws;
    float* bufA = (float*)(ws + BUFA_OFF);
    float* bufB = (float*)(ws + BUFB_OFF);
    int4*  bins = (int4*)(ws + BUFA_OFF);   // aliased: dead before ego buffers used
    int2*  cv   = (int2*)(ws + CV_OFF);
    int*   rs   = (int*)(ws + RS_OFF);
    int*   bcnt = (int*)(ws + SMALL_OFF);
    int*   bbase= (int*)(ws + SMALL_OFF + 3200);
    int*   gcur = (int*)(ws + SMALL_OFF + 6400);
    float* nrm  = (float*)(ws + NRM_OFF);

    float* accF = (float*)d_out;
    float* clF  = (float*)d_out + (size_t)N_NODES * EMB;

    // ---- CSR build (must precede ego memcpys: bins aliases bufA/bufB) ----
    hipMemsetAsync(bcnt, 0, NBUCK * sizeof(int), stream);
    const int NBLK = (N_EDGES + EPB - 1) / EPB;  // 1563
    k_bcount<<<NBLK, 256, 0, stream>>>(adj_rows, bcnt);
    k_scan782<<<1, 1024, 0, stream>>>(bcnt, bbase, gcur, rs);
    k_bin<<<NBLK, 256, 0, stream>>>(adj_rows, adj_cols, adj_vals, gcur, bins);
    k_build<<<NBUCK, 256, 0, stream>>>(bins, bcnt, bbase, cv, rs);

    // ego0 = concat(user_emb, item_emb)
    hipMemcpyAsync(bufA, user_emb, (size_t)USER_NUM * EMB * sizeof(float),
                   hipMemcpyDeviceToDevice, stream);
    hipMemcpyAsync(bufA + (size_t)USER_NUM * EMB, item_emb,
                   (size_t)(N_NODES - USER_NUM) * EMB * sizeof(float),
                   hipMemcpyDeviceToDevice, stream);

    // ---- 3 layers ----
    const int T16 = N_NODES * 16;
    for (int k = 0; k < 3; ++k) {
        float* x = (k & 1) ? bufB : bufA;
        float* y = (k & 1) ? bufA : bufB;
        const float* nk = noise + (size_t)k * N_NODES * EMB;
        k_spmm<<<(T16 + 255) / 256, 256, 0, stream>>>(rs, cv, x, y);
        k_norm<<<(N_NODES + 127) / 128, 128, 0, stream>>>(nk, nrm);
        k_epi<<<(T16 + 255) / 256, 256, 0, stream>>>(y, nk, nrm, accF, clF, k);
    }
}

// Round 2
// 1592.238 us; speedup vs baseline: 1.1934x; 1.0379x over previous
//
#include <hip/hip_runtime.h>

// GCLSDA encoder: ego=concat(U,I); 3x { ego = A@ego; ego += sign(ego)*nhat*0.1; acc+=ego }
// Outputs: final=acc/3, cl=ego_layer1.
// Numerics: SpMM accumulates per (row,dim) sequentially in ascending edge-index
// order with separate _rn mul/add (matches np.add.at); norm uses numpy
// pairwise-sum 8-accumulator pattern. This exact order passed round 1
// (absmax 1.22e-4) — the CSR build below reproduces the IDENTICAL cv order.
//
// CSR build v3: bucket = row>>8 (782 buckets).
//  A1 k_bcount : per-bucket edge counts, LDS-aggregated.
//  k_scan782   : exclusive scan -> bbase, gcur; rs[N]=E.
//  A2 k_bin    : append {col,val,key} to bucket region.
//  B  k_build  : one WG per bucket; rank-based single-write CSR (530us->~??,
//                fell out of top-5 in R1). Keys unique ((rl<<24)|e): final
//                slot = start[rl] + #{same-row keys < mine}; LDS-only rank
//                scan, each cv entry written EXACTLY ONCE.
//                KEY RECOVERY MUST BE LOGICAL SHIFT: (unsigned)key>>24.
//
// SpMM v2 (R2): was latency-bound (VALUBusy 17%, 42% HBM, dep chain
// cv[j+1]->x[col] with ~1-edge prefetch distance). Now 3-edge groups with a
// 3-stage cv queue: cv loaded 2 groups ahead of its x-gather; x-rows fetched
// 1 full group (~540 cyc across 6 waves/SIMD) ahead of consumption.
// Prefetch indices clamp to N_EDGES-1 (past-row cv = valid other-row entries
// -> valid cols -> safe addresses); out-of-row edges predicated to v=0
// (adding +/-0 is exact). Active-edge accumulation order is bit-identical.

#define USER_NUM 100000
#define N_NODES  200000
#define EMB      64
#define N_EDGES  6400000
#define NBUCK    782        // ceil(200000/256)
#define CAP      9216       // max edges/bucket on LDS fast path (mu=8192, +11 sigma)
#define EPB      4096       // edges per block in A1/A2

static constexpr size_t BUFA_OFF  = 0;
static constexpr size_t BUFB_OFF  = 51200000;
static constexpr size_t CV_OFF    = 102400000;
static constexpr size_t RS_OFF    = 153600000;
static constexpr size_t SMALL_OFF = 154400016;
static constexpr size_t NRM_OFF   = 155200016;
static constexpr size_t WS_NEED   = 156000016;

// ---- Pass A1: bucket counts ----
__global__ void k_bcount(const int* __restrict__ rows, int* __restrict__ bcnt) {
    __shared__ int h[NBUCK];
    for (int i = threadIdx.x; i < NBUCK; i += 256) h[i] = 0;
    __syncthreads();
    int base = blockIdx.x * EPB;
    for (int k = 0; k < EPB / 256; ++k) {
        int e = base + k * 256 + threadIdx.x;
        if (e < N_EDGES) atomicAdd(&h[rows[e] >> 8], 1);
    }
    __syncthreads();
    for (int i = threadIdx.x; i < NBUCK; i += 256) {
        int c = h[i];
        if (c) atomicAdd(&bcnt[i], c);
    }
}

// ---- scan of 782 bucket counts -> bbase (exclusive), gcur; rs[N]=E ----
__global__ void k_scan782(const int* __restrict__ bcnt, int* __restrict__ bbase,
                          int* __restrict__ gcur, int* __restrict__ rs) {
    __shared__ int s[1024];
    int i = threadIdx.x;
    int v = (i < NBUCK) ? bcnt[i] : 0;
    s[i] = v;
    __syncthreads();
    for (int off = 1; off < 1024; off <<= 1) {
        int t = 0;
        if (i >= off) t = s[i - off];
        __syncthreads();
        s[i] += t;
        __syncthreads();
    }
    if (i < NBUCK) {
        int ex = s[i] - v;
        bbase[i] = ex;
        gcur[i] = ex;
    }
    if (i == 0) rs[N_NODES] = N_EDGES;
}

// ---- Pass A2: bin edges into bucket regions ----
__global__ void k_bin(const int* __restrict__ rows, const int* __restrict__ cols,
                      const float* __restrict__ vals, int* __restrict__ gcur,
                      int4* __restrict__ bins) {
    __shared__ int h[NBUCK];
    __shared__ int gb[NBUCK];
    for (int i = threadIdx.x; i < NBUCK; i += 256) h[i] = 0;
    __syncthreads();
    int base = blockIdx.x * EPB;
    int myr[EPB / 256];
    int myrank[EPB / 256];
    for (int k = 0; k < EPB / 256; ++k) {
        int e = base + k * 256 + threadIdx.x;
        myr[k] = -1;
        if (e < N_EDGES) {
            int r = rows[e];
            myr[k] = r;
            myrank[k] = atomicAdd(&h[r >> 8], 1);
        }
    }
    __syncthreads();
    for (int i = threadIdx.x; i < NBUCK; i += 256) {
        int c = h[i];
        if (c) gb[i] = atomicAdd(&gcur[i], c);
    }
    __syncthreads();
    for (int k = 0; k < EPB / 256; ++k) {
        int e = base + k * 256 + threadIdx.x;
        int r = myr[k];
        if (r >= 0) {
            int b = r >> 8;
            int pos = gb[b] + myrank[k];
            int key = ((r & 255) << 24) | e;   // e < 2^23, row-local in top byte
            bins[pos] = make_int4(cols[e], __float_as_int(vals[e]), key, 0);
        }
    }
}

// ---- Pass B: per-bucket row-grouping + stable (edge-idx) ordering -> cv, rs ----
__global__ __launch_bounds__(256) void k_build(int4* __restrict__ bins,
                                               const int* __restrict__ bcnt,
                                               const int* __restrict__ bbase,
                                               int2* __restrict__ cv,
                                               int* __restrict__ rs) {
    __shared__ int cnt[256];
    __shared__ int start[256];
    __shared__ int cur[256];
    __shared__ int scanbuf[256];
    __shared__ int eKey[CAP];     // grouped keys (fast path)
    __shared__ short idxS[CAP];   // grouped -> bins-local index (fast path)
    int tid = threadIdx.x;
    int b = blockIdx.x;
    int n = bcnt[b];
    int base = bbase[b];
    int rowbase = b << 8;
    cnt[tid] = 0;
    __syncthreads();
    // step 1: per-row-local histogram (LOGICAL shift: rl in [0,255])
    for (int i = tid; i < n; i += 256) {
        unsigned key = (unsigned)bins[base + i].z;
        atomicAdd(&cnt[key >> 24], 1);
    }
    __syncthreads();
    // exclusive scan of cnt -> start
    int v = cnt[tid];
    scanbuf[tid] = v;
    __syncthreads();
    for (int off = 1; off < 256; off <<= 1) {
        int t = 0;
        if (tid >= off) t = scanbuf[tid - off];
        __syncthreads();
        scanbuf[tid] += t;
        __syncthreads();
    }
    start[tid] = scanbuf[tid] - v;
    {
        int row = rowbase + tid;
        if (row < N_NODES) rs[row] = base + start[tid];
    }
    cur[tid] = 0;
    __syncthreads();
    if (n <= CAP) {
        // step 2: group keys by row into LDS (intra-row order arbitrary here)
        for (int i = tid; i < n; i += 256) {
            int key = bins[base + i].z;                 // L2-hot re-read
            int rl = (int)((unsigned)key >> 24);
            int p = start[rl] + atomicAdd(&cur[rl], 1);
            eKey[p] = key;
            idxS[p] = (short)i;
        }
        __syncthreads();
        // step 3: rank = #{same-row keys < mine} -> final slot; write cv ONCE.
        for (int p = tid; p < n; p += 256) {
            int k = eKey[p];
            int rl = (int)((unsigned)k >> 24);
            int s0 = start[rl];
            int s1 = s0 + cnt[rl];
            int rank = 0;
            int q = s0;
            for (; q + 4 <= s1; q += 4) {
                rank += (eKey[q]     < k);
                rank += (eKey[q + 1] < k);
                rank += (eKey[q + 2] < k);
                rank += (eKey[q + 3] < k);
            }
            for (; q < s1; ++q) rank += (eKey[q] < k);
            int4 e4 = bins[base + (int)idxS[p]];        // random within 147KB, L2-hot
            cv[base + s0 + rank] = make_int2(e4.x, e4.y);
        }
    } else {
        // overflow fallback (statistically unreachable, +11 sigma): keys in
        // bins[].w, global insertion sort (slow but correct for any input).
        for (int i = tid; i < n; i += 256) {
            int4 e4 = bins[base + i];
            int rl = (int)((unsigned)e4.z >> 24);
            int p = start[rl] + atomicAdd(&cur[rl], 1);
            cv[base + p] = make_int2(e4.x, e4.y);
            bins[base + p].w = e4.z;
        }
        __syncthreads();
        int c = cnt[tid];
        if (c > 1) {
            int s0 = start[tid];
            int s1 = s0 + c;
            for (int i = s0 + 1; i < s1; ++i) {
                int ke = bins[base + i].w;
                int2 kv = cv[base + i];
                int j = i - 1;
                while (j >= s0 && bins[base + j].w > ke) {
                    bins[base + j + 1].w = bins[base + j].w;
                    cv[base + j + 1] = cv[base + j];
                    --j;
                }
                bins[base + j + 1].w = ke;
                cv[base + j + 1] = kv;
            }
        }
    }
}

// ---- SpMM v2: one thread per (row, 4-dim group); 3-edge pipelined groups.
// cv queue: curY (values being accumulated), nxt (cols for next x-prefetch),
// nn (in flight). x-rows prefetched one full group ahead of consumption.
// Active-edge accumulate order identical to v1 (ascending edge idx, _rn ops).
__global__ __launch_bounds__(256) void k_spmm(const int* __restrict__ rs,
                                              const int2* __restrict__ cv,
                                              const float* __restrict__ x,
                                              float* __restrict__ y) {
    int t = blockIdx.x * blockDim.x + threadIdx.x;
    if (t >= N_NODES * 16) return;
    int r = t >> 4;
    int c = (t & 15) << 2;
    int j0 = rs[r], j1 = rs[r + 1];
    float a0 = 0.f, a1 = 0.f, a2 = 0.f, a3 = 0.f;
    if (j0 < j1) {
        const int EMAX = N_EDGES - 1;
        const float* xc = x + c;   // per-thread column base
        // prologue: cv for groups 0,1,2; x for group 0
        int2 c0 = cv[j0];
        int2 c1 = cv[min(j0 + 1, EMAX)];
        int2 c2 = cv[min(j0 + 2, EMAX)];
        int2 n0 = cv[min(j0 + 3, EMAX)];
        int2 n1 = cv[min(j0 + 4, EMAX)];
        int2 n2 = cv[min(j0 + 5, EMAX)];
        int2 m0 = cv[min(j0 + 6, EMAX)];
        int2 m1 = cv[min(j0 + 7, EMAX)];
        int2 m2 = cv[min(j0 + 8, EMAX)];
        float4 x0 = *(const float4*)(xc + c0.x * EMB);
        float4 x1 = *(const float4*)(xc + c1.x * EMB);
        float4 x2 = *(const float4*)(xc + c2.x * EMB);
        for (int j = j0; j < j1; j += 3) {
            // x prefetch for next group (cv loaded >=1 full iteration ago)
            float4 y0 = *(const float4*)(xc + n0.x * EMB);
            float4 y1 = *(const float4*)(xc + n1.x * EMB);
            float4 y2 = *(const float4*)(xc + n2.x * EMB);
            // accumulate current group (predicate out-of-row edges to v=0;
            // a + (+/-0) is exact, so active-edge order/values unchanged)
            float v0 = __int_as_float(c0.y);
            float v1 = (j + 1 < j1) ? __int_as_float(c1.y) : 0.f;
            float v2 = (j + 2 < j1) ? __int_as_float(c2.y) : 0.f;
            a0 = __fadd_rn(a0, __fmul_rn(v0, x0.x));
            a1 = __fadd_rn(a1, __fmul_rn(v0, x0.y));
            a2 = __fadd_rn(a2, __fmul_rn(v0, x0.z));
            a3 = __fadd_rn(a3, __fmul_rn(v0, x0.w));
            a0 = __fadd_rn(a0, __fmul_rn(v1, x1.x));
            a1 = __fadd_rn(a1, __fmul_rn(v1, x1.y));
            a2 = __fadd_rn(a2, __fmul_rn(v1, x1.z));
            a3 = __fadd_rn(a3, __fmul_rn(v1, x1.w));
            a0 = __fadd_rn(a0, __fmul_rn(v2, x2.x));
            a1 = __fadd_rn(a1, __fmul_rn(v2, x2.y));
            a2 = __fadd_rn(a2, __fmul_rn(v2, x2.z));
            a3 = __fadd_rn(a3, __fmul_rn(v2, x2.w));
            // rotate pipeline
            c0 = n0; c1 = n1; c2 = n2;
            n0 = m0; n1 = m1; n2 = m2;
            x0 = y0; x1 = y1; x2 = y2;
            // streaming cv prefetch, 2 groups ahead of its x-gather
            m0 = cv[min(j + 9,  EMAX)];
            m1 = cv[min(j + 10, EMAX)];
            m2 = cv[min(j + 11, EMAX)];
        }
    }
    *(float4*)(y + r * EMB + c) = make_float4(a0, a1, a2, a3);
}

// ---- per-row L2 norm of noise, numpy pairwise order (8 accumulators, n=64) ----
__global__ void k_norm(const float* __restrict__ nk, float* __restrict__ nrm) {
    __shared__ float tile[2][64 * 65];
    int wave = threadIdx.x >> 6;
    int lane = threadIdx.x & 63;
    int base = blockIdx.x * 128 + wave * 64;
    for (int rr = 0; rr < 64; ++rr) {
        int row = base + rr;
        float v = 0.f;
        if (row < N_NODES) v = nk[row * EMB + lane];
        tile[wave][rr * 65 + lane] = v;
    }
    __syncthreads();
    int row = base + lane;
    if (row < N_NODES) {
        const float* tp = &tile[wave][lane * 65];
        float rj[8];
        #pragma unroll
        for (int j = 0; j < 8; ++j) {
            float xj = tp[j];
            rj[j] = __fmul_rn(xj, xj);
        }
        #pragma unroll
        for (int i = 8; i < 64; i += 8) {
            #pragma unroll
            for (int j = 0; j < 8; ++j) {
                float xj = tp[i + j];
                rj[j] = __fadd_rn(rj[j], __fmul_rn(xj, xj));
            }
        }
        float s01 = __fadd_rn(rj[0], rj[1]);
        float s23 = __fadd_rn(rj[2], rj[3]);
        float s45 = __fadd_rn(rj[4], rj[5]);
        float s67 = __fadd_rn(rj[6], rj[7]);
        float ss = __fadd_rn(__fadd_rn(s01, s23), __fadd_rn(s45, s67));
        float nv = __fsqrt_rn(ss);
        nv = fmaxf(nv, 1e-12f);
        nrm[row] = nv;
    }
}

// ---- epilogue: perturb, acc update, cl capture ----
__global__ void k_epi(float* __restrict__ ego, const float* __restrict__ nk,
                      const float* __restrict__ nrm, float* __restrict__ accF,
                      float* __restrict__ clF, int mode) {
    int t = blockIdx.x * blockDim.x + threadIdx.x;
    if (t >= N_NODES * 16) return;
    int r = t >> 4;
    int idx = t << 2;
    float4 y4 = *(float4*)(ego + idx);
    float4 n4 = *(const float4*)(nk + idx);
    float nv = nrm[r];
    float4 e4;
    {
        float s, q;
        s = (y4.x > 0.f) ? 1.f : ((y4.x < 0.f) ? -1.f : 0.f);
        q = __fdiv_rn(n4.x, nv);
        e4.x = __fadd_rn(y4.x, __fmul_rn(__fmul_rn(s, q), 0.1f));
        s = (y4.y > 0.f) ? 1.f : ((y4.y < 0.f) ? -1.f : 0.f);
        q = __fdiv_rn(n4.y, nv);
        e4.y = __fadd_rn(y4.y, __fmul_rn(__fmul_rn(s, q), 0.1f));
        s = (y4.z > 0.f) ? 1.f : ((y4.z < 0.f) ? -1.f : 0.f);
        q = __fdiv_rn(n4.z, nv);
        e4.z = __fadd_rn(y4.z, __fmul_rn(__fmul_rn(s, q), 0.1f));
        s = (y4.w > 0.f) ? 1.f : ((y4.w < 0.f) ? -1.f : 0.f);
        q = __fdiv_rn(n4.w, nv);
        e4.w = __fadd_rn(y4.w, __fmul_rn(__fmul_rn(s, q), 0.1f));
    }
    *(float4*)(ego + idx) = e4;
    if (mode == 0) {
        *(float4*)(accF + idx) = e4;
        *(float4*)(clF + idx) = e4;
    } else if (mode == 1) {
        float4 a = *(float4*)(accF + idx);
        a.x = __fadd_rn(a.x, e4.x);
        a.y = __fadd_rn(a.y, e4.y);
        a.z = __fadd_rn(a.z, e4.z);
        a.w = __fadd_rn(a.w, e4.w);
        *(float4*)(accF + idx) = a;
    } else {
        float4 a = *(float4*)(accF + idx);
        float4 f;
        f.x = __fdiv_rn(__fadd_rn(a.x, e4.x), 3.0f);
        f.y = __fdiv_rn(__fadd_rn(a.y, e4.y), 3.0f);
        f.z = __fdiv_rn(__fadd_rn(a.z, e4.z), 3.0f);
        f.w = __fdiv_rn(__fadd_rn(a.w, e4.w), 3.0f);
        *(float4*)(accF + idx) = f;
    }
}

extern "C" void kernel_launch(void* const* d_in, const int* in_sizes, int n_in,
                              void* d_out, int out_size, void* d_ws, size_t ws_size,
                              hipStream_t stream) {
    if (ws_size < WS_NEED) return;

    const float* user_emb = (const float*)d_in[0];
    const float* item_emb = (const float*)d_in[1];
    const int*   adj_rows = (const int*)d_in[2];
    const int*   adj_cols = (const int*)d_in[3];
    const float* adj_vals = (const float*)d_in[4];
    const float* noise    = (const float*)d_in[5];

    char* ws = (char*)d_ws;
    float* bufA = (float*)(ws + BUFA_OFF);
    float* bufB = (float*)(ws + BUFB_OFF);
    int4*  bins = (int4*)(ws + BUFA_OFF);   // aliased: dead before ego buffers used
    int2*  cv   = (int2*)(ws + CV_OFF);
    int*   rs   = (int*)(ws + RS_OFF);
    int*   bcnt = (int*)(ws + SMALL_OFF);
    int*   bbase= (int*)(ws + SMALL_OFF + 3200);
    int*   gcur = (int*)(ws + SMALL_OFF + 6400);
    float* nrm  = (float*)(ws + NRM_OFF);

    float* accF = (float*)d_out;
    float* clF  = (float*)d_out + (size_t)N_NODES * EMB;

    // ---- CSR build (must precede ego memcpys: bins aliases bufA/bufB) ----
    hipMemsetAsync(bcnt, 0, NBUCK * sizeof(int), stream);
    const int NBLK = (N_EDGES + EPB - 1) / EPB;  // 1563
    k_bcount<<<NBLK, 256, 0, stream>>>(adj_rows, bcnt);
    k_scan782<<<1, 1024, 0, stream>>>(bcnt, bbase, gcur, rs);
    k_bin<<<NBLK, 256, 0, stream>>>(adj_rows, adj_cols, adj_vals, gcur, bins);
    k_build<<<NBUCK, 256, 0, stream>>>(bins, bcnt, bbase, cv, rs);

    // ego0 = concat(user_emb, item_emb)
    hipMemcpyAsync(bufA, user_emb, (size_t)USER_NUM * EMB * sizeof(float),
                   hipMemcpyDeviceToDevice, stream);
    hipMemcpyAsync(bufA + (size_t)USER_NUM * EMB, item_emb,
                   (size_t)(N_NODES - USER_NUM) * EMB * sizeof(float),
                   hipMemcpyDeviceToDevice, stream);

    // ---- 3 layers ----
    const int T16 = N_NODES * 16;
    for (int k = 0; k < 3; ++k) {
        float* x = (k & 1) ? bufB : bufA;
        float* y = (k & 1) ? bufA : bufB;
        const float* nk = noise + (size_t)k * N_NODES * EMB;
        k_spmm<<<(T16 + 255) / 256, 256, 0, stream>>>(rs, cv, x, y);
        k_norm<<<(N_NODES + 127) / 128, 128, 0, stream>>>(nk, nrm);
        k_epi<<<(T16 + 255) / 256, 256, 0, stream>>>(y, nk, nrm, accF, clF, k);
    }
}

// Round 4
// 1588.854 us; speedup vs baseline: 1.1959x; 1.0021x over previous
//
#include <hip/hip_runtime.h>

// GCLSDA encoder: ego=concat(U,I); 3x { ego = A@ego; ego += sign(ego)*nhat*0.1; acc+=ego }
// Outputs: final=acc/3, cl=ego_layer1.
// Numerics: SpMM accumulates per (row,dim) sequentially in ascending edge-index
// order with separate _rn mul/add (matches np.add.at); norm uses numpy
// pairwise-sum 8-accumulator pattern. Exact order is LOAD-BEARING: sign(ego)
// amplifies ~1e-7 reorder noise into ~1e-2 errors at near-zero ego elements.
// Do NOT reorder the per-row accumulation.
//
// R4 = R3 resubmit (R3 bench was an infra failure: "container failed twice",
// no verification result). Hardened two theoretical fault hazards:
//  * layer-0 virtual concat now selects {base, rebased col} IN-KERNEL
//    (no negative-offset pointer is ever formed on host);
//  * xlo is never nullptr (layers 1-2 pass x for both bases).
// R3 changes (traffic elimination — R2 showed spmm at an L2-miss service-rate
// limit ~3.8 TB/s, so deeper pipelining has low ROI):
//  * k_epi FUSED into k_spmm (same thread owns the same y element): deletes
//    the y write+read round trip, 306 MB total. VGPR must stay <=64 (m69
//    occupancy cliff halves waves/CU at 65) -> kept R2's 3-stage pipeline.
//  * layer-0 reads user/item DIRECTLY (two-base select), deleting the 51 MB
//    concat memcpys.
//  * bins split into keys[] (int) + cvb[] (int2): k_bin write 102->77 MB,
//    k_build histogram read 102->26 MB.
//  * dead stores dropped: mode0 accF (mode1 reads clF, bitwise equal) and
//    mode2 ego (dead after last layer).
//
// CSR build: bucket = row>>8 (782 buckets). A1 count -> scan -> A2 bin
// {key}+{col,val} -> B per-bucket rank-scatter (keys unique ((rl<<24)|e):
// final slot = start[rl] + #{same-row keys < mine}; each cv written ONCE).
// KEY RECOVERY MUST BE LOGICAL SHIFT: (unsigned)key>>24.

#define USER_NUM 100000
#define N_NODES  200000
#define EMB      64
#define N_EDGES  6400000
#define NBUCK    782        // ceil(200000/256)
#define CAP      9216       // max edges/bucket on LDS fast path (mu=8184, +11 sigma)
#define EPB      4096       // edges per block in A1/A2

static constexpr size_t BUFA_OFF  = 0;
static constexpr size_t BUFB_OFF  = 51200000;
static constexpr size_t CV_OFF    = 102400000;
static constexpr size_t RS_OFF    = 153600000;
static constexpr size_t SMALL_OFF = 154400016;
static constexpr size_t NRM_OFF   = 155200016;
static constexpr size_t WS_NEED   = 156000016;

// ---- Pass A1: bucket counts ----
__global__ void k_bcount(const int* __restrict__ rows, int* __restrict__ bcnt) {
    __shared__ int h[NBUCK];
    for (int i = threadIdx.x; i < NBUCK; i += 256) h[i] = 0;
    __syncthreads();
    int base = blockIdx.x * EPB;
    for (int k = 0; k < EPB / 256; ++k) {
        int e = base + k * 256 + threadIdx.x;
        if (e < N_EDGES) atomicAdd(&h[rows[e] >> 8], 1);
    }
    __syncthreads();
    for (int i = threadIdx.x; i < NBUCK; i += 256) {
        int c = h[i];
        if (c) atomicAdd(&bcnt[i], c);
    }
}

// ---- scan of 782 bucket counts -> bbase (exclusive), gcur; rs[N]=E ----
__global__ void k_scan782(const int* __restrict__ bcnt, int* __restrict__ bbase,
                          int* __restrict__ gcur, int* __restrict__ rs) {
    __shared__ int s[1024];
    int i = threadIdx.x;
    int v = (i < NBUCK) ? bcnt[i] : 0;
    s[i] = v;
    __syncthreads();
    for (int off = 1; off < 1024; off <<= 1) {
        int t = 0;
        if (i >= off) t = s[i - off];
        __syncthreads();
        s[i] += t;
        __syncthreads();
    }
    if (i < NBUCK) {
        int ex = s[i] - v;
        bbase[i] = ex;
        gcur[i] = ex;
    }
    if (i == 0) rs[N_NODES] = N_EDGES;
}

// ---- Pass A2: bin edges into bucket regions (split key / col-val arrays) ----
__global__ void k_bin(const int* __restrict__ rows, const int* __restrict__ cols,
                      const float* __restrict__ vals, int* __restrict__ gcur,
                      int* __restrict__ keys, int2* __restrict__ cvb) {
    __shared__ int h[NBUCK];
    __shared__ int gb[NBUCK];
    for (int i = threadIdx.x; i < NBUCK; i += 256) h[i] = 0;
    __syncthreads();
    int base = blockIdx.x * EPB;
    int myr[EPB / 256];
    int myrank[EPB / 256];
    for (int k = 0; k < EPB / 256; ++k) {
        int e = base + k * 256 + threadIdx.x;
        myr[k] = -1;
        if (e < N_EDGES) {
            int r = rows[e];
            myr[k] = r;
            myrank[k] = atomicAdd(&h[r >> 8], 1);
        }
    }
    __syncthreads();
    for (int i = threadIdx.x; i < NBUCK; i += 256) {
        int c = h[i];
        if (c) gb[i] = atomicAdd(&gcur[i], c);
    }
    __syncthreads();
    for (int k = 0; k < EPB / 256; ++k) {
        int e = base + k * 256 + threadIdx.x;
        int r = myr[k];
        if (r >= 0) {
            int b = r >> 8;
            int pos = gb[b] + myrank[k];
            keys[pos] = ((r & 255) << 24) | e;  // e < 2^23, row-local in top byte
            cvb[pos] = make_int2(cols[e], __float_as_int(vals[e]));
        }
    }
}

// ---- Pass B: per-bucket row-grouping + stable (edge-idx) ordering -> cv, rs ----
__global__ __launch_bounds__(256) void k_build(const int* __restrict__ keys,
                                               const int2* __restrict__ cvb,
                                               const int* __restrict__ bcnt,
                                               const int* __restrict__ bbase,
                                               int2* __restrict__ cv,
                                               int* __restrict__ rs) {
    __shared__ int cnt[256];
    __shared__ int start[256];
    __shared__ int cur[256];
    __shared__ int scanbuf[256];
    __shared__ int eKey[CAP];              // grouped keys (fast path)
    __shared__ unsigned short idxS[CAP];   // grouped -> bucket-local src index
    int tid = threadIdx.x;
    int b = blockIdx.x;
    int n = bcnt[b];
    int base = bbase[b];
    int rowbase = b << 8;
    cnt[tid] = 0;
    __syncthreads();
    // step 1: per-row-local histogram (LOGICAL shift: rl in [0,255])
    for (int i = tid; i < n; i += 256) {
        unsigned key = (unsigned)keys[base + i];
        atomicAdd(&cnt[key >> 24], 1);
    }
    __syncthreads();
    // exclusive scan of cnt -> start
    int v = cnt[tid];
    scanbuf[tid] = v;
    __syncthreads();
    for (int off = 1; off < 256; off <<= 1) {
        int t = 0;
        if (tid >= off) t = scanbuf[tid - off];
        __syncthreads();
        scanbuf[tid] += t;
        __syncthreads();
    }
    start[tid] = scanbuf[tid] - v;
    {
        int row = rowbase + tid;
        if (row < N_NODES) rs[row] = base + start[tid];
    }
    cur[tid] = 0;
    __syncthreads();
    if (n <= CAP) {
        // step 2: group keys by row into LDS (intra-row order arbitrary here)
        for (int i = tid; i < n; i += 256) {
            int key = keys[base + i];                   // L2-hot re-read (36KB)
            int rl = (int)((unsigned)key >> 24);
            int p = start[rl] + atomicAdd(&cur[rl], 1);
            eKey[p] = key;
            idxS[p] = (unsigned short)i;
        }
        __syncthreads();
        // step 3: rank = #{same-row keys < mine} -> final slot; write cv ONCE.
        // Keys unique => bijection; same top byte within a row => signed cmp
        // orders by edge idx. Independent LDS reads, no serial chains.
        for (int p = tid; p < n; p += 256) {
            int k = eKey[p];
            int rl = (int)((unsigned)k >> 24);
            int s0 = start[rl];
            int s1 = s0 + cnt[rl];
            int rank = 0;
            int q = s0;
            for (; q + 4 <= s1; q += 4) {
                rank += (eKey[q]     < k);
                rank += (eKey[q + 1] < k);
                rank += (eKey[q + 2] < k);
                rank += (eKey[q + 3] < k);
            }
            for (; q < s1; ++q) rank += (eKey[q] < k);
            cv[base + s0 + rank] = cvb[base + (int)idxS[p]];  // L2-hot (74KB)
        }
    } else {
        // overflow fallback (statistically unreachable, +11 sigma):
        // group (key, srcidx) pairs into cv region, per-row insertion sort by
        // key (global, slow but correct), then rewrite each slot from cvb.
        for (int i = tid; i < n; i += 256) {
            int key = keys[base + i];
            int rl = (int)((unsigned)key >> 24);
            int p = start[rl] + atomicAdd(&cur[rl], 1);
            cv[base + p] = make_int2(key, i);
        }
        __syncthreads();
        int c = cnt[tid];
        if (c > 1) {
            int s0 = start[tid];
            int s1 = s0 + c;
            for (int i = s0 + 1; i < s1; ++i) {
                int2 kv = cv[base + i];
                int j = i - 1;
                while (j >= s0 && cv[base + j].x > kv.x) {
                    cv[base + j + 1] = cv[base + j];
                    --j;
                }
                cv[base + j + 1] = kv;
            }
        }
        __syncthreads();
        // each slot read exactly once by its own thread, then overwritten
        for (int i = tid; i < n; i += 256) {
            int2 pr = cv[base + i];
            cv[base + i] = cvb[base + pr.y];
        }
    }
}

// ---- per-row L2 norm of noise, numpy pairwise order (8 accumulators, n=64) ----
__global__ void k_norm(const float* __restrict__ nk, float* __restrict__ nrm) {
    __shared__ float tile[2][64 * 65];
    int wave = threadIdx.x >> 6;
    int lane = threadIdx.x & 63;
    int base = blockIdx.x * 128 + wave * 64;
    for (int rr = 0; rr < 64; ++rr) {
        int row = base + rr;
        float v = 0.f;
        if (row < N_NODES) v = nk[row * EMB + lane];
        tile[wave][rr * 65 + lane] = v;
    }
    __syncthreads();
    int row = base + lane;
    if (row < N_NODES) {
        const float* tp = &tile[wave][lane * 65];
        float rj[8];
        #pragma unroll
        for (int j = 0; j < 8; ++j) {
            float xj = tp[j];
            rj[j] = __fmul_rn(xj, xj);
        }
        #pragma unroll
        for (int i = 8; i < 64; i += 8) {
            #pragma unroll
            for (int j = 0; j < 8; ++j) {
                float xj = tp[i + j];
                rj[j] = __fadd_rn(rj[j], __fmul_rn(xj, xj));
            }
        }
        float s01 = __fadd_rn(rj[0], rj[1]);
        float s23 = __fadd_rn(rj[2], rj[3]);
        float s45 = __fadd_rn(rj[4], rj[5]);
        float s67 = __fadd_rn(rj[6], rj[7]);
        float ss = __fadd_rn(__fadd_rn(s01, s23), __fadd_rn(s45, s67));
        float nv = __fsqrt_rn(ss);
        nv = fmaxf(nv, 1e-12f);
        nrm[row] = nv;
    }
}

// ---- Fused SpMM + epilogue. One thread per (row, 4-dim group).
// 3-edge pipelined groups (R2 structure, <=64 VGPR). x gather selects
// {base, rebased col} in-kernel: layer 0 reads user/item directly
// (split=100000); layers 1-2 pass split=0 and xlo=xhi (select is inert,
// no OOB pointer ever formed).
// Epilogue: e4 = y + sign(y)*nk/nrm*0.1;
//   mode0: ego=e4, clF=e4            (accF deferred — mode1 reads clF)
//   mode1: ego=e4, accF=clF+e4
//   mode2: accF=(accF+e4)/3          (ego dead, not written)
__global__ __launch_bounds__(256) void k_fused(const int* __restrict__ rs,
                                               const int2* __restrict__ cv,
                                               const float* __restrict__ xlo,
                                               const float* __restrict__ xhi,
                                               int split,
                                               const float* __restrict__ nk,
                                               const float* __restrict__ nrm,
                                               float* __restrict__ ego,
                                               float* __restrict__ accF,
                                               float* __restrict__ clF,
                                               int mode) {
    int t = blockIdx.x * blockDim.x + threadIdx.x;
    if (t >= N_NODES * 16) return;
    int r = t >> 4;
    int c = (t & 15) << 2;
    int j0 = rs[r], j1 = rs[r + 1];
    float a0 = 0.f, a1 = 0.f, a2 = 0.f, a3 = 0.f;
    if (j0 < j1) {
        const int EMAX = N_EDGES - 1;
        // two-base gather: base and rebased column selected together
        #define XROW(col) (((col) < split ? xlo : xhi) + \
                           ((col) < split ? (col) : (col) - split) * EMB + c)
        int2 c0 = cv[j0];
        int2 c1 = cv[min(j0 + 1, EMAX)];
        int2 c2 = cv[min(j0 + 2, EMAX)];
        int2 n0 = cv[min(j0 + 3, EMAX)];
        int2 n1 = cv[min(j0 + 4, EMAX)];
        int2 n2 = cv[min(j0 + 5, EMAX)];
        int2 m0 = cv[min(j0 + 6, EMAX)];
        int2 m1 = cv[min(j0 + 7, EMAX)];
        int2 m2 = cv[min(j0 + 8, EMAX)];
        float4 x0 = *(const float4*)XROW(c0.x);
        float4 x1 = *(const float4*)XROW(c1.x);
        float4 x2 = *(const float4*)XROW(c2.x);
        for (int j = j0; j < j1; j += 3) {
            // x prefetch for next group (cv loaded 2 iterations ago)
            float4 y0 = *(const float4*)XROW(n0.x);
            float4 y1 = *(const float4*)XROW(n1.x);
            float4 y2 = *(const float4*)XROW(n2.x);
            // accumulate current group (predicate out-of-row edges to v=0;
            // a + (+/-0) is exact, so active-edge order/values unchanged)
            float v0 = __int_as_float(c0.y);
            float v1 = (j + 1 < j1) ? __int_as_float(c1.y) : 0.f;
            float v2 = (j + 2 < j1) ? __int_as_float(c2.y) : 0.f;
            a0 = __fadd_rn(a0, __fmul_rn(v0, x0.x));
            a1 = __fadd_rn(a1, __fmul_rn(v0, x0.y));
            a2 = __fadd_rn(a2, __fmul_rn(v0, x0.z));
            a3 = __fadd_rn(a3, __fmul_rn(v0, x0.w));
            a0 = __fadd_rn(a0, __fmul_rn(v1, x1.x));
            a1 = __fadd_rn(a1, __fmul_rn(v1, x1.y));
            a2 = __fadd_rn(a2, __fmul_rn(v1, x1.z));
            a3 = __fadd_rn(a3, __fmul_rn(v1, x1.w));
            a0 = __fadd_rn(a0, __fmul_rn(v2, x2.x));
            a1 = __fadd_rn(a1, __fmul_rn(v2, x2.y));
            a2 = __fadd_rn(a2, __fmul_rn(v2, x2.z));
            a3 = __fadd_rn(a3, __fmul_rn(v2, x2.w));
            // rotate pipeline
            c0 = n0; c1 = n1; c2 = n2;
            n0 = m0; n1 = m1; n2 = m2;
            x0 = y0; x1 = y1; x2 = y2;
            // streaming cv prefetch, 2 groups ahead of its x-gather
            m0 = cv[min(j + 9,  EMAX)];
            m1 = cv[min(j + 10, EMAX)];
            m2 = cv[min(j + 11, EMAX)];
        }
        #undef XROW
    }
    // ---- fused epilogue (identical math/order to the old k_epi) ----
    int idx = t << 2;
    float4 n4 = *(const float4*)(nk + idx);
    float nv = nrm[r];
    float4 e4;
    {
        float s, q;
        s = (a0 > 0.f) ? 1.f : ((a0 < 0.f) ? -1.f : 0.f);
        q = __fdiv_rn(n4.x, nv);
        e4.x = __fadd_rn(a0, __fmul_rn(__fmul_rn(s, q), 0.1f));
        s = (a1 > 0.f) ? 1.f : ((a1 < 0.f) ? -1.f : 0.f);
        q = __fdiv_rn(n4.y, nv);
        e4.y = __fadd_rn(a1, __fmul_rn(__fmul_rn(s, q), 0.1f));
        s = (a2 > 0.f) ? 1.f : ((a2 < 0.f) ? -1.f : 0.f);
        q = __fdiv_rn(n4.z, nv);
        e4.z = __fadd_rn(a2, __fmul_rn(__fmul_rn(s, q), 0.1f));
        s = (a3 > 0.f) ? 1.f : ((a3 < 0.f) ? -1.f : 0.f);
        q = __fdiv_rn(n4.w, nv);
        e4.w = __fadd_rn(a3, __fmul_rn(__fmul_rn(s, q), 0.1f));
    }
    if (mode == 0) {
        *(float4*)(ego + idx) = e4;
        *(float4*)(clF + idx) = e4;
    } else if (mode == 1) {
        *(float4*)(ego + idx) = e4;
        float4 a = *(const float4*)(clF + idx);   // == acc after layer 0
        a.x = __fadd_rn(a.x, e4.x);
        a.y = __fadd_rn(a.y, e4.y);
        a.z = __fadd_rn(a.z, e4.z);
        a.w = __fadd_rn(a.w, e4.w);
        *(float4*)(accF + idx) = a;
    } else {
        float4 a = *(const float4*)(accF + idx);
        float4 f;
        f.x = __fdiv_rn(__fadd_rn(a.x, e4.x), 3.0f);
        f.y = __fdiv_rn(__fadd_rn(a.y, e4.y), 3.0f);
        f.z = __fdiv_rn(__fadd_rn(a.z, e4.z), 3.0f);
        f.w = __fdiv_rn(__fadd_rn(a.w, e4.w), 3.0f);
        *(float4*)(accF + idx) = f;
    }
}

extern "C" void kernel_launch(void* const* d_in, const int* in_sizes, int n_in,
                              void* d_out, int out_size, void* d_ws, size_t ws_size,
                              hipStream_t stream) {
    if (ws_size < WS_NEED) return;

    const float* user_emb = (const float*)d_in[0];
    const float* item_emb = (const float*)d_in[1];
    const int*   adj_rows = (const int*)d_in[2];
    const int*   adj_cols = (const int*)d_in[3];
    const float* adj_vals = (const float*)d_in[4];
    const float* noise    = (const float*)d_in[5];

    char* ws = (char*)d_ws;
    float* bufA = (float*)(ws + BUFA_OFF);
    float* bufB = (float*)(ws + BUFB_OFF);
    int*   keys = (int*)(ws + BUFA_OFF);    // aliased: dead before bufA first write
    int2*  cvb  = (int2*)(ws + BUFB_OFF);   // aliased: dead before bufB first write
    int2*  cv   = (int2*)(ws + CV_OFF);
    int*   rs   = (int*)(ws + RS_OFF);
    int*   bcnt = (int*)(ws + SMALL_OFF);
    int*   bbase= (int*)(ws + SMALL_OFF + 3200);
    int*   gcur = (int*)(ws + SMALL_OFF + 6400);
    float* nrm  = (float*)(ws + NRM_OFF);

    float* accF = (float*)d_out;
    float* clF  = (float*)d_out + (size_t)N_NODES * EMB;

    // ---- CSR build (keys/cvb alias bufA/bufB: build completes before any
    //      fused layer writes ego into those buffers; single stream) ----
    hipMemsetAsync(bcnt, 0, NBUCK * sizeof(int), stream);
    const int NBLK = (N_EDGES + EPB - 1) / EPB;  // 1563
    k_bcount<<<NBLK, 256, 0, stream>>>(adj_rows, bcnt);
    k_scan782<<<1, 1024, 0, stream>>>(bcnt, bbase, gcur, rs);
    k_bin<<<NBLK, 256, 0, stream>>>(adj_rows, adj_cols, adj_vals, gcur, keys, cvb);
    k_build<<<NBUCK, 256, 0, stream>>>(keys, cvb, bcnt, bbase, cv, rs);

    // ---- 3 layers: norm(k) then fused spmm+epilogue(k) ----
    const int T16 = N_NODES * 16;
    for (int k = 0; k < 3; ++k) {
        const float* nkp = noise + (size_t)k * N_NODES * EMB;
        const float* xlo  = (k == 0) ? user_emb : ((k == 1) ? bufA : bufB);
        const float* xhi  = (k == 0) ? item_emb : ((k == 1) ? bufA : bufB);
        int split = (k == 0) ? USER_NUM : 0;
        float* ego_out = (k == 0) ? bufA : bufB;   // k==2 never writes ego
        k_norm<<<(N_NODES + 127) / 128, 128, 0, stream>>>(nkp, nrm);
        k_fused<<<(T16 + 255) / 256, 256, 0, stream>>>(rs, cv, xlo, xhi, split,
                                                       nkp, nrm, ego_out, accF,
                                                       clF, k);
    }
}

// Round 5
// 1578.087 us; speedup vs baseline: 1.2041x; 1.0068x over previous
//
#include <hip/hip_runtime.h>

// GCLSDA encoder: ego=concat(U,I); 3x { ego = A@ego; ego += sign(ego)*nhat*0.1; acc+=ego }
// Outputs: final=acc/3, cl=ego_layer1.
// Numerics: SpMM accumulates per (row,dim) sequentially in ascending edge-index
// order with separate _rn mul/add (matches np.add.at); norm uses numpy
// pairwise-sum 8-accumulator pattern. Exact order is LOAD-BEARING: sign(ego)
// amplifies ~1e-7 reorder noise into ~1e-2 errors at near-zero ego elements.
// Do NOT reorder the per-row accumulation.
//
// R5: k_bin rewrite. R4 showed k_bin at 310us with WRITE_SIZE=379MB vs 77MB
// payload (~5x line amplification: EPB=4096 -> ~5-edge runs per bucket, each
// dirtying mostly-empty 64B lines). Root cause of small EPB was the per-thread
// rank cache (EPB/256 VGPRs). Insight: intra-bucket bins order is ARBITRARY
// (k_build orders purely by key and rs comes from the histogram), so rank can
// be RECOMPUTED in phase 2 via a fresh LDS atomicAdd pass over re-read rows
// (L2-hot) instead of cached. No per-thread arrays -> EPB=16384 -> ~21-edge
// runs -> ~1.3x amplification. k_bcount gets the same EPB.
// R3/R4 (verified): k_epi fused into spmm (-306MB); layer-0 virtual concat
// (in-kernel {base, rebased col} select, no OOB pointer); keys/cvb split;
// dead stores dropped (mode0 accF deferred to mode1 via clF; mode2 ego dead).
//
// CSR build: bucket = row>>8 (782 buckets). A1 count -> scan -> A2 bin
// {key}+{col,val} -> B per-bucket rank-scatter (keys unique ((rl<<24)|e):
// final slot = start[rl] + #{same-row keys < mine}; each cv written ONCE).
// KEY RECOVERY MUST BE LOGICAL SHIFT: (unsigned)key>>24.

#define USER_NUM 100000
#define N_NODES  200000
#define EMB      64
#define N_EDGES  6400000
#define NBUCK    782        // ceil(200000/256)
#define CAP      9216       // max edges/bucket on LDS fast path (mu=8184, +11 sigma)
#define EPB      16384      // edges per block in A1/A2 (no per-thread caches)

static constexpr size_t BUFA_OFF  = 0;
static constexpr size_t BUFB_OFF  = 51200000;
static constexpr size_t CV_OFF    = 102400000;
static constexpr size_t RS_OFF    = 153600000;
static constexpr size_t SMALL_OFF = 154400016;
static constexpr size_t NRM_OFF   = 155200016;
static constexpr size_t WS_NEED   = 156000016;

// ---- Pass A1: bucket counts ----
__global__ void k_bcount(const int* __restrict__ rows, int* __restrict__ bcnt) {
    __shared__ int h[NBUCK];
    for (int i = threadIdx.x; i < NBUCK; i += 256) h[i] = 0;
    __syncthreads();
    int base = blockIdx.x * EPB;
    int end  = min(base + EPB, N_EDGES);
    for (int e = base + threadIdx.x; e < end; e += 256)
        atomicAdd(&h[rows[e] >> 8], 1);
    __syncthreads();
    for (int i = threadIdx.x; i < NBUCK; i += 256) {
        int c = h[i];
        if (c) atomicAdd(&bcnt[i], c);
    }
}

// ---- scan of 782 bucket counts -> bbase (exclusive), gcur; rs[N]=E ----
__global__ void k_scan782(const int* __restrict__ bcnt, int* __restrict__ bbase,
                          int* __restrict__ gcur, int* __restrict__ rs) {
    __shared__ int s[1024];
    int i = threadIdx.x;
    int v = (i < NBUCK) ? bcnt[i] : 0;
    s[i] = v;
    __syncthreads();
    for (int off = 1; off < 1024; off <<= 1) {
        int t = 0;
        if (i >= off) t = s[i - off];
        __syncthreads();
        s[i] += t;
        __syncthreads();
    }
    if (i < NBUCK) {
        int ex = s[i] - v;
        bbase[i] = ex;
        gcur[i] = ex;
    }
    if (i == 0) rs[N_NODES] = N_EDGES;
}

// ---- Pass A2: bin edges into bucket regions (split key / col-val arrays).
// Phase 1: LDS histogram over this block's EPB edges. Phase 2: one global
// reservation per non-empty bucket. Phase 3: re-read rows (L2-hot 64KB),
// recompute rank via fresh LDS atomicAdd — intra-bucket order is arbitrary
// (k_build sorts by key), so the recomputed permutation is valid. ----
__global__ void k_bin(const int* __restrict__ rows, const int* __restrict__ cols,
                      const float* __restrict__ vals, int* __restrict__ gcur,
                      int* __restrict__ keys, int2* __restrict__ cvb) {
    __shared__ int h[NBUCK];
    __shared__ int gb[NBUCK];
    for (int i = threadIdx.x; i < NBUCK; i += 256) h[i] = 0;
    __syncthreads();
    int base = blockIdx.x * EPB;
    int end  = min(base + EPB, N_EDGES);
    for (int e = base + threadIdx.x; e < end; e += 256)
        atomicAdd(&h[rows[e] >> 8], 1);
    __syncthreads();
    for (int i = threadIdx.x; i < NBUCK; i += 256) {
        int c = h[i];
        gb[i] = c ? atomicAdd(&gcur[i], c) : 0;
        h[i] = 0;
    }
    __syncthreads();
    for (int e = base + threadIdx.x; e < end; e += 256) {
        int r = rows[e];
        int b = r >> 8;
        int pos = gb[b] + atomicAdd(&h[b], 1);
        keys[pos] = ((r & 255) << 24) | e;  // e < 2^23, row-local in top byte
        cvb[pos] = make_int2(cols[e], __float_as_int(vals[e]));
    }
}

// ---- Pass B: per-bucket row-grouping + stable (edge-idx) ordering -> cv, rs ----
__global__ __launch_bounds__(256) void k_build(const int* __restrict__ keys,
                                               const int2* __restrict__ cvb,
                                               const int* __restrict__ bcnt,
                                               const int* __restrict__ bbase,
                                               int2* __restrict__ cv,
                                               int* __restrict__ rs) {
    __shared__ int cnt[256];
    __shared__ int start[256];
    __shared__ int cur[256];
    __shared__ int scanbuf[256];
    __shared__ int eKey[CAP];              // grouped keys (fast path)
    __shared__ unsigned short idxS[CAP];   // grouped -> bucket-local src index
    int tid = threadIdx.x;
    int b = blockIdx.x;
    int n = bcnt[b];
    int base = bbase[b];
    int rowbase = b << 8;
    cnt[tid] = 0;
    __syncthreads();
    // step 1: per-row-local histogram (LOGICAL shift: rl in [0,255])
    for (int i = tid; i < n; i += 256) {
        unsigned key = (unsigned)keys[base + i];
        atomicAdd(&cnt[key >> 24], 1);
    }
    __syncthreads();
    // exclusive scan of cnt -> start
    int v = cnt[tid];
    scanbuf[tid] = v;
    __syncthreads();
    for (int off = 1; off < 256; off <<= 1) {
        int t = 0;
        if (tid >= off) t = scanbuf[tid - off];
        __syncthreads();
        scanbuf[tid] += t;
        __syncthreads();
    }
    start[tid] = scanbuf[tid] - v;
    {
        int row = rowbase + tid;
        if (row < N_NODES) rs[row] = base + start[tid];
    }
    cur[tid] = 0;
    __syncthreads();
    if (n <= CAP) {
        // step 2: group keys by row into LDS (intra-row order arbitrary here)
        for (int i = tid; i < n; i += 256) {
            int key = keys[base + i];                   // L2-hot re-read
            int rl = (int)((unsigned)key >> 24);
            int p = start[rl] + atomicAdd(&cur[rl], 1);
            eKey[p] = key;
            idxS[p] = (unsigned short)i;
        }
        __syncthreads();
        // step 3: rank = #{same-row keys < mine} -> final slot; write cv ONCE.
        // Keys unique => bijection; same top byte within a row => signed cmp
        // orders by edge idx. Independent LDS reads, no serial chains.
        for (int p = tid; p < n; p += 256) {
            int k = eKey[p];
            int rl = (int)((unsigned)k >> 24);
            int s0 = start[rl];
            int s1 = s0 + cnt[rl];
            int rank = 0;
            int q = s0;
            for (; q + 4 <= s1; q += 4) {
                rank += (eKey[q]     < k);
                rank += (eKey[q + 1] < k);
                rank += (eKey[q + 2] < k);
                rank += (eKey[q + 3] < k);
            }
            for (; q < s1; ++q) rank += (eKey[q] < k);
            cv[base + s0 + rank] = cvb[base + (int)idxS[p]];  // L2-hot
        }
    } else {
        // overflow fallback (statistically unreachable, +11 sigma):
        // group (key, srcidx) pairs into cv region, per-row insertion sort by
        // key (global, slow but correct), then rewrite each slot from cvb.
        for (int i = tid; i < n; i += 256) {
            int key = keys[base + i];
            int rl = (int)((unsigned)key >> 24);
            int p = start[rl] + atomicAdd(&cur[rl], 1);
            cv[base + p] = make_int2(key, i);
        }
        __syncthreads();
        int c = cnt[tid];
        if (c > 1) {
            int s0 = start[tid];
            int s1 = s0 + c;
            for (int i = s0 + 1; i < s1; ++i) {
                int2 kv = cv[base + i];
                int j = i - 1;
                while (j >= s0 && cv[base + j].x > kv.x) {
                    cv[base + j + 1] = cv[base + j];
                    --j;
                }
                cv[base + j + 1] = kv;
            }
        }
        __syncthreads();
        // each slot read exactly once by its own thread, then overwritten
        for (int i = tid; i < n; i += 256) {
            int2 pr = cv[base + i];
            cv[base + i] = cvb[base + pr.y];
        }
    }
}

// ---- per-row L2 norm of noise, numpy pairwise order (8 accumulators, n=64) ----
__global__ void k_norm(const float* __restrict__ nk, float* __restrict__ nrm) {
    __shared__ float tile[2][64 * 65];
    int wave = threadIdx.x >> 6;
    int lane = threadIdx.x & 63;
    int base = blockIdx.x * 128 + wave * 64;
    for (int rr = 0; rr < 64; ++rr) {
        int row = base + rr;
        float v = 0.f;
        if (row < N_NODES) v = nk[row * EMB + lane];
        tile[wave][rr * 65 + lane] = v;
    }
    __syncthreads();
    int row = base + lane;
    if (row < N_NODES) {
        const float* tp = &tile[wave][lane * 65];
        float rj[8];
        #pragma unroll
        for (int j = 0; j < 8; ++j) {
            float xj = tp[j];
            rj[j] = __fmul_rn(xj, xj);
        }
        #pragma unroll
        for (int i = 8; i < 64; i += 8) {
            #pragma unroll
            for (int j = 0; j < 8; ++j) {
                float xj = tp[i + j];
                rj[j] = __fadd_rn(rj[j], __fmul_rn(xj, xj));
            }
        }
        float s01 = __fadd_rn(rj[0], rj[1]);
        float s23 = __fadd_rn(rj[2], rj[3]);
        float s45 = __fadd_rn(rj[4], rj[5]);
        float s67 = __fadd_rn(rj[6], rj[7]);
        float ss = __fadd_rn(__fadd_rn(s01, s23), __fadd_rn(s45, s67));
        float nv = __fsqrt_rn(ss);
        nv = fmaxf(nv, 1e-12f);
        nrm[row] = nv;
    }
}

// ---- Fused SpMM + epilogue. One thread per (row, 4-dim group).
// 3-edge pipelined groups (R2 structure, <=64 VGPR). x gather selects
// {base, rebased col} in-kernel: layer 0 reads user/item directly
// (split=100000); layers 1-2 pass split=0 and xlo=xhi (select is inert,
// no OOB pointer ever formed).
// Epilogue: e4 = y + sign(y)*nk/nrm*0.1;
//   mode0: ego=e4, clF=e4            (accF deferred — mode1 reads clF)
//   mode1: ego=e4, accF=clF+e4
//   mode2: accF=(accF+e4)/3          (ego dead, not written)
__global__ __launch_bounds__(256) void k_fused(const int* __restrict__ rs,
                                               const int2* __restrict__ cv,
                                               const float* __restrict__ xlo,
                                               const float* __restrict__ xhi,
                                               int split,
                                               const float* __restrict__ nk,
                                               const float* __restrict__ nrm,
                                               float* __restrict__ ego,
                                               float* __restrict__ accF,
                                               float* __restrict__ clF,
                                               int mode) {
    int t = blockIdx.x * blockDim.x + threadIdx.x;
    if (t >= N_NODES * 16) return;
    int r = t >> 4;
    int c = (t & 15) << 2;
    int j0 = rs[r], j1 = rs[r + 1];
    float a0 = 0.f, a1 = 0.f, a2 = 0.f, a3 = 0.f;
    if (j0 < j1) {
        const int EMAX = N_EDGES - 1;
        // two-base gather: base and rebased column selected together
        #define XROW(col) (((col) < split ? xlo : xhi) + \
                           ((col) < split ? (col) : (col) - split) * EMB + c)
        int2 c0 = cv[j0];
        int2 c1 = cv[min(j0 + 1, EMAX)];
        int2 c2 = cv[min(j0 + 2, EMAX)];
        int2 n0 = cv[min(j0 + 3, EMAX)];
        int2 n1 = cv[min(j0 + 4, EMAX)];
        int2 n2 = cv[min(j0 + 5, EMAX)];
        int2 m0 = cv[min(j0 + 6, EMAX)];
        int2 m1 = cv[min(j0 + 7, EMAX)];
        int2 m2 = cv[min(j0 + 8, EMAX)];
        float4 x0 = *(const float4*)XROW(c0.x);
        float4 x1 = *(const float4*)XROW(c1.x);
        float4 x2 = *(const float4*)XROW(c2.x);
        for (int j = j0; j < j1; j += 3) {
            // x prefetch for next group (cv loaded 2 iterations ago)
            float4 y0 = *(const float4*)XROW(n0.x);
            float4 y1 = *(const float4*)XROW(n1.x);
            float4 y2 = *(const float4*)XROW(n2.x);
            // accumulate current group (predicate out-of-row edges to v=0;
            // a + (+/-0) is exact, so active-edge order/values unchanged)
            float v0 = __int_as_float(c0.y);
            float v1 = (j + 1 < j1) ? __int_as_float(c1.y) : 0.f;
            float v2 = (j + 2 < j1) ? __int_as_float(c2.y) : 0.f;
            a0 = __fadd_rn(a0, __fmul_rn(v0, x0.x));
            a1 = __fadd_rn(a1, __fmul_rn(v0, x0.y));
            a2 = __fadd_rn(a2, __fmul_rn(v0, x0.z));
            a3 = __fadd_rn(a3, __fmul_rn(v0, x0.w));
            a0 = __fadd_rn(a0, __fmul_rn(v1, x1.x));
            a1 = __fadd_rn(a1, __fmul_rn(v1, x1.y));
            a2 = __fadd_rn(a2, __fmul_rn(v1, x1.z));
            a3 = __fadd_rn(a3, __fmul_rn(v1, x1.w));
            a0 = __fadd_rn(a0, __fmul_rn(v2, x2.x));
            a1 = __fadd_rn(a1, __fmul_rn(v2, x2.y));
            a2 = __fadd_rn(a2, __fmul_rn(v2, x2.z));
            a3 = __fadd_rn(a3, __fmul_rn(v2, x2.w));
            // rotate pipeline
            c0 = n0; c1 = n1; c2 = n2;
            n0 = m0; n1 = m1; n2 = m2;
            x0 = y0; x1 = y1; x2 = y2;
            // streaming cv prefetch, 2 groups ahead of its x-gather
            m0 = cv[min(j + 9,  EMAX)];
            m1 = cv[min(j + 10, EMAX)];
            m2 = cv[min(j + 11, EMAX)];
        }
        #undef XROW
    }
    // ---- fused epilogue (identical math/order to the old k_epi) ----
    int idx = t << 2;
    float4 n4 = *(const float4*)(nk + idx);
    float nv = nrm[r];
    float4 e4;
    {
        float s, q;
        s = (a0 > 0.f) ? 1.f : ((a0 < 0.f) ? -1.f : 0.f);
        q = __fdiv_rn(n4.x, nv);
        e4.x = __fadd_rn(a0, __fmul_rn(__fmul_rn(s, q), 0.1f));
        s = (a1 > 0.f) ? 1.f : ((a1 < 0.f) ? -1.f : 0.f);
        q = __fdiv_rn(n4.y, nv);
        e4.y = __fadd_rn(a1, __fmul_rn(__fmul_rn(s, q), 0.1f));
        s = (a2 > 0.f) ? 1.f : ((a2 < 0.f) ? -1.f : 0.f);
        q = __fdiv_rn(n4.z, nv);
        e4.z = __fadd_rn(a2, __fmul_rn(__fmul_rn(s, q), 0.1f));
        s = (a3 > 0.f) ? 1.f : ((a3 < 0.f) ? -1.f : 0.f);
        q = __fdiv_rn(n4.w, nv);
        e4.w = __fadd_rn(a3, __fmul_rn(__fmul_rn(s, q), 0.1f));
    }
    if (mode == 0) {
        *(float4*)(ego + idx) = e4;
        *(float4*)(clF + idx) = e4;
    } else if (mode == 1) {
        *(float4*)(ego + idx) = e4;
        float4 a = *(const float4*)(clF + idx);   // == acc after layer 0
        a.x = __fadd_rn(a.x, e4.x);
        a.y = __fadd_rn(a.y, e4.y);
        a.z = __fadd_rn(a.z, e4.z);
        a.w = __fadd_rn(a.w, e4.w);
        *(float4*)(accF + idx) = a;
    } else {
        float4 a = *(const float4*)(accF + idx);
        float4 f;
        f.x = __fdiv_rn(__fadd_rn(a.x, e4.x), 3.0f);
        f.y = __fdiv_rn(__fadd_rn(a.y, e4.y), 3.0f);
        f.z = __fdiv_rn(__fadd_rn(a.z, e4.z), 3.0f);
        f.w = __fdiv_rn(__fadd_rn(a.w, e4.w), 3.0f);
        *(float4*)(accF + idx) = f;
    }
}

extern "C" void kernel_launch(void* const* d_in, const int* in_sizes, int n_in,
                              void* d_out, int out_size, void* d_ws, size_t ws_size,
                              hipStream_t stream) {
    if (ws_size < WS_NEED) return;

    const float* user_emb = (const float*)d_in[0];
    const float* item_emb = (const float*)d_in[1];
    const int*   adj_rows = (const int*)d_in[2];
    const int*   adj_cols = (const int*)d_in[3];
    const float* adj_vals = (const float*)d_in[4];
    const float* noise    = (const float*)d_in[5];

    char* ws = (char*)d_ws;
    float* bufA = (float*)(ws + BUFA_OFF);
    float* bufB = (float*)(ws + BUFB_OFF);
    int*   keys = (int*)(ws + BUFA_OFF);    // aliased: dead before bufA first write
    int2*  cvb  = (int2*)(ws + BUFB_OFF);   // aliased: dead before bufB first write
    int2*  cv   = (int2*)(ws + CV_OFF);
    int*   rs   = (int*)(ws + RS_OFF);
    int*   bcnt = (int*)(ws + SMALL_OFF);
    int*   bbase= (int*)(ws + SMALL_OFF + 3200);
    int*   gcur = (int*)(ws + SMALL_OFF + 6400);
    float* nrm  = (float*)(ws + NRM_OFF);

    float* accF = (float*)d_out;
    float* clF  = (float*)d_out + (size_t)N_NODES * EMB;

    // ---- CSR build (keys/cvb alias bufA/bufB: build completes before any
    //      fused layer writes ego into those buffers; single stream) ----
    hipMemsetAsync(bcnt, 0, NBUCK * sizeof(int), stream);
    const int NBLK = (N_EDGES + EPB - 1) / EPB;  // 391
    k_bcount<<<NBLK, 256, 0, stream>>>(adj_rows, bcnt);
    k_scan782<<<1, 1024, 0, stream>>>(bcnt, bbase, gcur, rs);
    k_bin<<<NBLK, 256, 0, stream>>>(adj_rows, adj_cols, adj_vals, gcur, keys, cvb);
    k_build<<<NBUCK, 256, 0, stream>>>(keys, cvb, bcnt, bbase, cv, rs);

    // ---- 3 layers: norm(k) then fused spmm+epilogue(k) ----
    const int T16 = N_NODES * 16;
    for (int k = 0; k < 3; ++k) {
        const float* nkp = noise + (size_t)k * N_NODES * EMB;
        const float* xlo  = (k == 0) ? user_emb : ((k == 1) ? bufA : bufB);
        const float* xhi  = (k == 0) ? item_emb : ((k == 1) ? bufA : bufB);
        int split = (k == 0) ? USER_NUM : 0;
        float* ego_out = (k == 0) ? bufA : bufB;   // k==2 never writes ego
        k_norm<<<(N_NODES + 127) / 128, 128, 0, stream>>>(nkp, nrm);
        k_fused<<<(T16 + 255) / 256, 256, 0, stream>>>(rs, cv, xlo, xhi, split,
                                                       nkp, nrm, ego_out, accF,
                                                       clF, k);
    }
}

// Round 6
// 1508.982 us; speedup vs baseline: 1.2592x; 1.0458x over previous
//
#include <hip/hip_runtime.h>

// GCLSDA encoder: ego=concat(U,I); 3x { ego = A@ego; ego += sign(ego)*nhat*0.1; acc+=ego }
// Outputs: final=acc/3, cl=ego_layer1.
// Numerics: SpMM accumulates per (row,dim) sequentially in ascending edge-index
// order with separate _rn mul/add (matches np.add.at); norm uses numpy
// pairwise-sum 8-accumulator pattern. Exact order is LOAD-BEARING: sign(ego)
// amplifies ~1e-7 reorder noise into ~1e-2 errors at near-zero ego elements.
// Do NOT reorder the per-row accumulation.
//
// R6: keys-only binning. R5 post-mortem: k_bin's 4.5x write amplification is
// TEMPORAL — lines fill over the whole block lifetime while per-XCD write
// footprint (~9MB) exceeds 4MB L2, so lines evict partially-dirty repeatedly;
// run length barely matters. Fix = shrink payload: cvb[] is REDUNDANT (edge
// idx e is embedded in every key; cols/vals are immutable inputs), so k_bin
// writes keys only (4B/edge, 25.6MB) and k_build gathers (cols[e],vals[e])
// at final-scatter time (random 4B reads into 51MB — LLC-resident). k_bin
// blocks widened to 1024 threads (24 waves/CU; was 14% occupancy).
// R5 (verified): rank recomputed in k_bin phase 3 via fresh LDS atomicAdd
// (intra-bucket order arbitrary — k_build sorts by key); EPB=16384.
// R3/R4 (verified): k_epi fused into spmm; layer-0 virtual concat (in-kernel
// {base, rebased col} select); dead stores dropped (mode0 accF deferred via
// clF; mode2 ego dead).
//
// CSR build: bucket = row>>8 (782 buckets). A1 count -> scan -> A2 bin {key}
// -> B per-bucket rank-scatter (keys unique ((rl<<24)|e): final slot =
// start[rl] + #{same-row keys < mine}; each cv written ONCE).
// KEY RECOVERY MUST BE LOGICAL SHIFT: (unsigned)key>>24. e = key & 0xFFFFFF.

#define USER_NUM 100000
#define N_NODES  200000
#define EMB      64
#define N_EDGES  6400000
#define NBUCK    782        // ceil(200000/256)
#define CAP      9216       // max edges/bucket on LDS fast path (mu=8184, +11 sigma)
#define EPB      16384      // edges per block in A1/A2
#define TB_A     1024       // threads per block in A1/A2

static constexpr size_t BUFA_OFF  = 0;
static constexpr size_t BUFB_OFF  = 51200000;
static constexpr size_t CV_OFF    = 102400000;
static constexpr size_t RS_OFF    = 153600000;
static constexpr size_t SMALL_OFF = 154400016;
static constexpr size_t NRM_OFF   = 155200016;
static constexpr size_t WS_NEED   = 156000016;

// ---- Pass A1: bucket counts ----
__global__ __launch_bounds__(TB_A) void k_bcount(const int* __restrict__ rows,
                                                 int* __restrict__ bcnt) {
    __shared__ int h[NBUCK];
    for (int i = threadIdx.x; i < NBUCK; i += TB_A) h[i] = 0;
    __syncthreads();
    int base = blockIdx.x * EPB;
    int end  = min(base + EPB, N_EDGES);
    for (int e = base + threadIdx.x; e < end; e += TB_A)
        atomicAdd(&h[rows[e] >> 8], 1);
    __syncthreads();
    for (int i = threadIdx.x; i < NBUCK; i += TB_A) {
        int c = h[i];
        if (c) atomicAdd(&bcnt[i], c);
    }
}

// ---- scan of 782 bucket counts -> bbase (exclusive), gcur; rs[N]=E ----
__global__ void k_scan782(const int* __restrict__ bcnt, int* __restrict__ bbase,
                          int* __restrict__ gcur, int* __restrict__ rs) {
    __shared__ int s[1024];
    int i = threadIdx.x;
    int v = (i < NBUCK) ? bcnt[i] : 0;
    s[i] = v;
    __syncthreads();
    for (int off = 1; off < 1024; off <<= 1) {
        int t = 0;
        if (i >= off) t = s[i - off];
        __syncthreads();
        s[i] += t;
        __syncthreads();
    }
    if (i < NBUCK) {
        int ex = s[i] - v;
        bbase[i] = ex;
        gcur[i] = ex;
    }
    if (i == 0) rs[N_NODES] = N_EDGES;
}

// ---- Pass A2: bin edge KEYS into bucket regions (keys only — cols/vals are
// gathered later via the embedded edge index). Phase 1: LDS histogram.
// Phase 2: one global reservation per non-empty bucket. Phase 3: re-read rows
// (L2-hot), recompute rank via fresh LDS atomicAdd — intra-bucket order is
// arbitrary (k_build sorts by key). ----
__global__ __launch_bounds__(TB_A) void k_bin(const int* __restrict__ rows,
                                              int* __restrict__ gcur,
                                              int* __restrict__ keys) {
    __shared__ int h[NBUCK];
    __shared__ int gb[NBUCK];
    for (int i = threadIdx.x; i < NBUCK; i += TB_A) h[i] = 0;
    __syncthreads();
    int base = blockIdx.x * EPB;
    int end  = min(base + EPB, N_EDGES);
    for (int e = base + threadIdx.x; e < end; e += TB_A)
        atomicAdd(&h[rows[e] >> 8], 1);
    __syncthreads();
    for (int i = threadIdx.x; i < NBUCK; i += TB_A) {
        int c = h[i];
        gb[i] = c ? atomicAdd(&gcur[i], c) : 0;
        h[i] = 0;
    }
    __syncthreads();
    for (int e = base + threadIdx.x; e < end; e += TB_A) {
        int r = rows[e];
        int b = r >> 8;
        int pos = gb[b] + atomicAdd(&h[b], 1);
        keys[pos] = ((r & 255) << 24) | e;  // e < 2^23, row-local in top byte
    }
}

// ---- Pass B: per-bucket row-grouping + stable (edge-idx) ordering -> cv, rs.
// cols/vals gathered via e = key & 0xFFFFFF (read-only 51MB, LLC-resident). ----
__global__ __launch_bounds__(256) void k_build(const int* __restrict__ keys,
                                               const int* __restrict__ cols,
                                               const float* __restrict__ vals,
                                               const int* __restrict__ bcnt,
                                               const int* __restrict__ bbase,
                                               int2* __restrict__ cv,
                                               int* __restrict__ rs) {
    __shared__ int cnt[256];
    __shared__ int start[256];
    __shared__ int cur[256];
    __shared__ int scanbuf[256];
    __shared__ int eKey[CAP];     // grouped keys (fast path)
    int tid = threadIdx.x;
    int b = blockIdx.x;
    int n = bcnt[b];
    int base = bbase[b];
    int rowbase = b << 8;
    cnt[tid] = 0;
    __syncthreads();
    // step 1: per-row-local histogram (LOGICAL shift: rl in [0,255])
    for (int i = tid; i < n; i += 256) {
        unsigned key = (unsigned)keys[base + i];
        atomicAdd(&cnt[key >> 24], 1);
    }
    __syncthreads();
    // exclusive scan of cnt -> start
    int v = cnt[tid];
    scanbuf[tid] = v;
    __syncthreads();
    for (int off = 1; off < 256; off <<= 1) {
        int t = 0;
        if (tid >= off) t = scanbuf[tid - off];
        __syncthreads();
        scanbuf[tid] += t;
        __syncthreads();
    }
    start[tid] = scanbuf[tid] - v;
    {
        int row = rowbase + tid;
        if (row < N_NODES) rs[row] = base + start[tid];
    }
    cur[tid] = 0;
    __syncthreads();
    if (n <= CAP) {
        // step 2: group keys by row into LDS (intra-row order arbitrary here)
        for (int i = tid; i < n; i += 256) {
            int key = keys[base + i];                   // L2-hot re-read
            int rl = (int)((unsigned)key >> 24);
            int p = start[rl] + atomicAdd(&cur[rl], 1);
            eKey[p] = key;
        }
        __syncthreads();
        // step 3: rank = #{same-row keys < mine} -> final slot; write cv ONCE.
        // Keys unique => bijection; same top byte within a row => signed cmp
        // orders by edge idx. cols/vals gathered via embedded edge index.
        for (int p = tid; p < n; p += 256) {
            int k = eKey[p];
            int rl = (int)((unsigned)k >> 24);
            int s0 = start[rl];
            int s1 = s0 + cnt[rl];
            int rank = 0;
            int q = s0;
            for (; q + 4 <= s1; q += 4) {
                rank += (eKey[q]     < k);
                rank += (eKey[q + 1] < k);
                rank += (eKey[q + 2] < k);
                rank += (eKey[q + 3] < k);
            }
            for (; q < s1; ++q) rank += (eKey[q] < k);
            int e = k & 0x00FFFFFF;
            cv[base + s0 + rank] = make_int2(cols[e], __float_as_int(vals[e]));
        }
    } else {
        // overflow fallback (statistically unreachable, +11 sigma):
        // scatter keys into cv[].x, per-row insertion sort by key (global,
        // slow but correct), then rewrite each slot from cols/vals via e.
        for (int i = tid; i < n; i += 256) {
            int key = keys[base + i];
            int rl = (int)((unsigned)key >> 24);
            int p = start[rl] + atomicAdd(&cur[rl], 1);
            cv[base + p] = make_int2(key, 0);
        }
        __syncthreads();
        int c = cnt[tid];
        if (c > 1) {
            int s0 = start[tid];
            int s1 = s0 + c;
            for (int i = s0 + 1; i < s1; ++i) {
                int2 kv = cv[base + i];
                int j = i - 1;
                while (j >= s0 && cv[base + j].x > kv.x) {
                    cv[base + j + 1] = cv[base + j];
                    --j;
                }
                cv[base + j + 1] = kv;
            }
        }
        __syncthreads();
        // each slot read exactly once by its own thread, then overwritten
        for (int i = tid; i < n; i += 256) {
            int e = cv[base + i].x & 0x00FFFFFF;
            cv[base + i] = make_int2(cols[e], __float_as_int(vals[e]));
        }
    }
}

// ---- per-row L2 norm of noise, numpy pairwise order (8 accumulators, n=64) ----
__global__ void k_norm(const float* __restrict__ nk, float* __restrict__ nrm) {
    __shared__ float tile[2][64 * 65];
    int wave = threadIdx.x >> 6;
    int lane = threadIdx.x & 63;
    int base = blockIdx.x * 128 + wave * 64;
    for (int rr = 0; rr < 64; ++rr) {
        int row = base + rr;
        float v = 0.f;
        if (row < N_NODES) v = nk[row * EMB + lane];
        tile[wave][rr * 65 + lane] = v;
    }
    __syncthreads();
    int row = base + lane;
    if (row < N_NODES) {
        const float* tp = &tile[wave][lane * 65];
        float rj[8];
        #pragma unroll
        for (int j = 0; j < 8; ++j) {
            float xj = tp[j];
            rj[j] = __fmul_rn(xj, xj);
        }
        #pragma unroll
        for (int i = 8; i < 64; i += 8) {
            #pragma unroll
            for (int j = 0; j < 8; ++j) {
                float xj = tp[i + j];
                rj[j] = __fadd_rn(rj[j], __fmul_rn(xj, xj));
            }
        }
        float s01 = __fadd_rn(rj[0], rj[1]);
        float s23 = __fadd_rn(rj[2], rj[3]);
        float s45 = __fadd_rn(rj[4], rj[5]);
        float s67 = __fadd_rn(rj[6], rj[7]);
        float ss = __fadd_rn(__fadd_rn(s01, s23), __fadd_rn(s45, s67));
        float nv = __fsqrt_rn(ss);
        nv = fmaxf(nv, 1e-12f);
        nrm[row] = nv;
    }
}

// ---- Fused SpMM + epilogue. One thread per (row, 4-dim group).
// 3-edge pipelined groups (R2 structure, <=64 VGPR). x gather selects
// {base, rebased col} in-kernel: layer 0 reads user/item directly
// (split=100000); layers 1-2 pass split=0 and xlo=xhi (select is inert,
// no OOB pointer ever formed).
// Epilogue: e4 = y + sign(y)*nk/nrm*0.1;
//   mode0: ego=e4, clF=e4            (accF deferred — mode1 reads clF)
//   mode1: ego=e4, accF=clF+e4
//   mode2: accF=(accF+e4)/3          (ego dead, not written)
__global__ __launch_bounds__(256) void k_fused(const int* __restrict__ rs,
                                               const int2* __restrict__ cv,
                                               const float* __restrict__ xlo,
                                               const float* __restrict__ xhi,
                                               int split,
                                               const float* __restrict__ nk,
                                               const float* __restrict__ nrm,
                                               float* __restrict__ ego,
                                               float* __restrict__ accF,
                                               float* __restrict__ clF,
                                               int mode) {
    int t = blockIdx.x * blockDim.x + threadIdx.x;
    if (t >= N_NODES * 16) return;
    int r = t >> 4;
    int c = (t & 15) << 2;
    int j0 = rs[r], j1 = rs[r + 1];
    float a0 = 0.f, a1 = 0.f, a2 = 0.f, a3 = 0.f;
    if (j0 < j1) {
        const int EMAX = N_EDGES - 1;
        // two-base gather: base and rebased column selected together
        #define XROW(col) (((col) < split ? xlo : xhi) + \
                           ((col) < split ? (col) : (col) - split) * EMB + c)
        int2 c0 = cv[j0];
        int2 c1 = cv[min(j0 + 1, EMAX)];
        int2 c2 = cv[min(j0 + 2, EMAX)];
        int2 n0 = cv[min(j0 + 3, EMAX)];
        int2 n1 = cv[min(j0 + 4, EMAX)];
        int2 n2 = cv[min(j0 + 5, EMAX)];
        int2 m0 = cv[min(j0 + 6, EMAX)];
        int2 m1 = cv[min(j0 + 7, EMAX)];
        int2 m2 = cv[min(j0 + 8, EMAX)];
        float4 x0 = *(const float4*)XROW(c0.x);
        float4 x1 = *(const float4*)XROW(c1.x);
        float4 x2 = *(const float4*)XROW(c2.x);
        for (int j = j0; j < j1; j += 3) {
            // x prefetch for next group (cv loaded 2 iterations ago)
            float4 y0 = *(const float4*)XROW(n0.x);
            float4 y1 = *(const float4*)XROW(n1.x);
            float4 y2 = *(const float4*)XROW(n2.x);
            // accumulate current group (predicate out-of-row edges to v=0;
            // a + (+/-0) is exact, so active-edge order/values unchanged)
            float v0 = __int_as_float(c0.y);
            float v1 = (j + 1 < j1) ? __int_as_float(c1.y) : 0.f;
            float v2 = (j + 2 < j1) ? __int_as_float(c2.y) : 0.f;
            a0 = __fadd_rn(a0, __fmul_rn(v0, x0.x));
            a1 = __fadd_rn(a1, __fmul_rn(v0, x0.y));
            a2 = __fadd_rn(a2, __fmul_rn(v0, x0.z));
            a3 = __fadd_rn(a3, __fmul_rn(v0, x0.w));
            a0 = __fadd_rn(a0, __fmul_rn(v1, x1.x));
            a1 = __fadd_rn(a1, __fmul_rn(v1, x1.y));
            a2 = __fadd_rn(a2, __fmul_rn(v1, x1.z));
            a3 = __fadd_rn(a3, __fmul_rn(v1, x1.w));
            a0 = __fadd_rn(a0, __fmul_rn(v2, x2.x));
            a1 = __fadd_rn(a1, __fmul_rn(v2, x2.y));
            a2 = __fadd_rn(a2, __fmul_rn(v2, x2.z));
            a3 = __fadd_rn(a3, __fmul_rn(v2, x2.w));
            // rotate pipeline
            c0 = n0; c1 = n1; c2 = n2;
            n0 = m0; n1 = m1; n2 = m2;
            x0 = y0; x1 = y1; x2 = y2;
            // streaming cv prefetch, 2 groups ahead of its x-gather
            m0 = cv[min(j + 9,  EMAX)];
            m1 = cv[min(j + 10, EMAX)];
            m2 = cv[min(j + 11, EMAX)];
        }
        #undef XROW
    }
    // ---- fused epilogue (identical math/order to the old k_epi) ----
    int idx = t << 2;
    float4 n4 = *(const float4*)(nk + idx);
    float nv = nrm[r];
    float4 e4;
    {
        float s, q;
        s = (a0 > 0.f) ? 1.f : ((a0 < 0.f) ? -1.f : 0.f);
        q = __fdiv_rn(n4.x, nv);
        e4.x = __fadd_rn(a0, __fmul_rn(__fmul_rn(s, q), 0.1f));
        s = (a1 > 0.f) ? 1.f : ((a1 < 0.f) ? -1.f : 0.f);
        q = __fdiv_rn(n4.y, nv);
        e4.y = __fadd_rn(a1, __fmul_rn(__fmul_rn(s, q), 0.1f));
        s = (a2 > 0.f) ? 1.f : ((a2 < 0.f) ? -1.f : 0.f);
        q = __fdiv_rn(n4.z, nv);
        e4.z = __fadd_rn(a2, __fmul_rn(__fmul_rn(s, q), 0.1f));
        s = (a3 > 0.f) ? 1.f : ((a3 < 0.f) ? -1.f : 0.f);
        q = __fdiv_rn(n4.w, nv);
        e4.w = __fadd_rn(a3, __fmul_rn(__fmul_rn(s, q), 0.1f));
    }
    if (mode == 0) {
        *(float4*)(ego + idx) = e4;
        *(float4*)(clF + idx) = e4;
    } else if (mode == 1) {
        *(float4*)(ego + idx) = e4;
        float4 a = *(const float4*)(clF + idx);   // == acc after layer 0
        a.x = __fadd_rn(a.x, e4.x);
        a.y = __fadd_rn(a.y, e4.y);
        a.z = __fadd_rn(a.z, e4.z);
        a.w = __fadd_rn(a.w, e4.w);
        *(float4*)(accF + idx) = a;
    } else {
        float4 a = *(const float4*)(accF + idx);
        float4 f;
        f.x = __fdiv_rn(__fadd_rn(a.x, e4.x), 3.0f);
        f.y = __fdiv_rn(__fadd_rn(a.y, e4.y), 3.0f);
        f.z = __fdiv_rn(__fadd_rn(a.z, e4.z), 3.0f);
        f.w = __fdiv_rn(__fadd_rn(a.w, e4.w), 3.0f);
        *(float4*)(accF + idx) = f;
    }
}

extern "C" void kernel_launch(void* const* d_in, const int* in_sizes, int n_in,
                              void* d_out, int out_size, void* d_ws, size_t ws_size,
                              hipStream_t stream) {
    if (ws_size < WS_NEED) return;

    const float* user_emb = (const float*)d_in[0];
    const float* item_emb = (const float*)d_in[1];
    const int*   adj_rows = (const int*)d_in[2];
    const int*   adj_cols = (const int*)d_in[3];
    const float* adj_vals = (const float*)d_in[4];
    const float* noise    = (const float*)d_in[5];

    char* ws = (char*)d_ws;
    float* bufA = (float*)(ws + BUFA_OFF);
    float* bufB = (float*)(ws + BUFB_OFF);
    int*   keys = (int*)(ws + BUFA_OFF);    // aliased: dead before bufA first write
    int2*  cv   = (int2*)(ws + CV_OFF);
    int*   rs   = (int*)(ws + RS_OFF);
    int*   bcnt = (int*)(ws + SMALL_OFF);
    int*   bbase= (int*)(ws + SMALL_OFF + 3200);
    int*   gcur = (int*)(ws + SMALL_OFF + 6400);
    float* nrm  = (float*)(ws + NRM_OFF);

    float* accF = (float*)d_out;
    float* clF  = (float*)d_out + (size_t)N_NODES * EMB;

    // ---- CSR build (keys aliases bufA: build completes before any fused
    //      layer writes ego into it; single stream) ----
    hipMemsetAsync(bcnt, 0, NBUCK * sizeof(int), stream);
    const int NBLK = (N_EDGES + EPB - 1) / EPB;  // 391
    k_bcount<<<NBLK, TB_A, 0, stream>>>(adj_rows, bcnt);
    k_scan782<<<1, 1024, 0, stream>>>(bcnt, bbase, gcur, rs);
    k_bin<<<NBLK, TB_A, 0, stream>>>(adj_rows, gcur, keys);
    k_build<<<NBUCK, 256, 0, stream>>>(keys, adj_cols, adj_vals, bcnt, bbase,
                                       cv, rs);

    // ---- 3 layers: norm(k) then fused spmm+epilogue(k) ----
    const int T16 = N_NODES * 16;
    for (int k = 0; k < 3; ++k) {
        const float* nkp = noise + (size_t)k * N_NODES * EMB;
        const float* xlo  = (k == 0) ? user_emb : ((k == 1) ? bufA : bufB);
        const float* xhi  = (k == 0) ? item_emb : ((k == 1) ? bufA : bufB);
        int split = (k == 0) ? USER_NUM : 0;
        float* ego_out = (k == 0) ? bufA : bufB;   // k==2 never writes ego
        k_norm<<<(N_NODES + 127) / 128, 128, 0, stream>>>(nkp, nrm);
        k_fused<<<(T16 + 255) / 256, 256, 0, stream>>>(rs, cv, xlo, xhi, split,
                                                       nkp, nrm, ego_out, accF,
                                                       clF, k);
    }
}

// Round 7
// 1405.519 us; speedup vs baseline: 1.3519x; 1.0736x over previous
//
#include <hip/hip_runtime.h>

// GCLSDA encoder: ego=concat(U,I); 3x { ego = A@ego; ego += sign(ego)*nhat*0.1; acc+=ego }
// Outputs: final=acc/3, cl=ego_layer1.
// Numerics: SpMM accumulates per (row,dim) sequentially in ascending edge-index
// order with separate _rn mul/add (matches np.add.at); norm uses numpy
// pairwise-sum 8-accumulator pattern. Exact order is LOAD-BEARING: sign(ego)
// amplifies ~1e-7 reorder noise into ~1e-2 errors at near-zero ego elements.
// Do NOT reorder the per-row accumulation.
//
// R7: zipped gather. R6 post-mortem: k_build FETCH=752MB — the deferred
// (cols[e], vals[e]) gather hits TWO separate 25.6MB arrays, two 64B line
// fills per edge (~819MB); LLC random-line service is only ~3 TB/s, so that
// is 270us. Fix: k_prep (ex-k_bcount) additionally writes zip[e]={col,val}
// sequentially (51MB coalesced, ~25us); k_build gathers ONE line per edge
// (~410MB). Identical bytes land in cv — bit-identical outputs.
// R6 (verified): keys-only binning (cvb redundant: e embedded in key);
// k_bin at 1024 threads. R5 (verified): rank recomputed in k_bin phase 3
// (intra-bucket order arbitrary — k_build sorts by key); EPB=16384.
// R3/R4 (verified): k_epi fused into spmm; layer-0 virtual concat; dead
// stores dropped (mode0 accF deferred via clF; mode2 ego dead).
//
// CSR build: bucket = row>>8 (782 buckets). A1 prep (count+zip) -> scan ->
// A2 bin {key} -> B per-bucket rank-scatter (keys unique ((rl<<24)|e): final
// slot = start[rl] + #{same-row keys < mine}; each cv written ONCE).
// KEY RECOVERY MUST BE LOGICAL SHIFT: (unsigned)key>>24. e = key & 0xFFFFFF.
// Aliasing: keys=bufA (dead before layer-0 ego write), zip=bufB (dead before
// layer-1 ego write); k_build consumes both before any layer runs.

#define USER_NUM 100000
#define N_NODES  200000
#define EMB      64
#define N_EDGES  6400000
#define NBUCK    782        // ceil(200000/256)
#define CAP      9216       // max edges/bucket on LDS fast path (mu=8184, +11 sigma)
#define EPB      16384      // edges per block in A1/A2
#define TB_A     1024       // threads per block in A1/A2

static constexpr size_t BUFA_OFF  = 0;
static constexpr size_t BUFB_OFF  = 51200000;
static constexpr size_t CV_OFF    = 102400000;
static constexpr size_t RS_OFF    = 153600000;
static constexpr size_t SMALL_OFF = 154400016;
static constexpr size_t NRM_OFF   = 155200016;
static constexpr size_t WS_NEED   = 156000016;

// ---- Pass A1: bucket counts + zip write (cols/vals -> int2, coalesced) ----
__global__ __launch_bounds__(TB_A) void k_prep(const int* __restrict__ rows,
                                               const int* __restrict__ cols,
                                               const float* __restrict__ vals,
                                               int* __restrict__ bcnt,
                                               int2* __restrict__ zip) {
    __shared__ int h[NBUCK];
    for (int i = threadIdx.x; i < NBUCK; i += TB_A) h[i] = 0;
    __syncthreads();
    int base = blockIdx.x * EPB;
    int end  = min(base + EPB, N_EDGES);
    for (int e = base + threadIdx.x; e < end; e += TB_A) {
        atomicAdd(&h[rows[e] >> 8], 1);
        zip[e] = make_int2(cols[e], __float_as_int(vals[e]));
    }
    __syncthreads();
    for (int i = threadIdx.x; i < NBUCK; i += TB_A) {
        int c = h[i];
        if (c) atomicAdd(&bcnt[i], c);
    }
}

// ---- scan of 782 bucket counts -> bbase (exclusive), gcur; rs[N]=E ----
__global__ void k_scan782(const int* __restrict__ bcnt, int* __restrict__ bbase,
                          int* __restrict__ gcur, int* __restrict__ rs) {
    __shared__ int s[1024];
    int i = threadIdx.x;
    int v = (i < NBUCK) ? bcnt[i] : 0;
    s[i] = v;
    __syncthreads();
    for (int off = 1; off < 1024; off <<= 1) {
        int t = 0;
        if (i >= off) t = s[i - off];
        __syncthreads();
        s[i] += t;
        __syncthreads();
    }
    if (i < NBUCK) {
        int ex = s[i] - v;
        bbase[i] = ex;
        gcur[i] = ex;
    }
    if (i == 0) rs[N_NODES] = N_EDGES;
}

// ---- Pass A2: bin edge KEYS into bucket regions (keys only). Phase 1: LDS
// histogram. Phase 2: one global reservation per non-empty bucket. Phase 3:
// re-read rows (L2-hot), recompute rank via fresh LDS atomicAdd —
// intra-bucket order is arbitrary (k_build sorts by key). ----
__global__ __launch_bounds__(TB_A) void k_bin(const int* __restrict__ rows,
                                              int* __restrict__ gcur,
                                              int* __restrict__ keys) {
    __shared__ int h[NBUCK];
    __shared__ int gb[NBUCK];
    for (int i = threadIdx.x; i < NBUCK; i += TB_A) h[i] = 0;
    __syncthreads();
    int base = blockIdx.x * EPB;
    int end  = min(base + EPB, N_EDGES);
    for (int e = base + threadIdx.x; e < end; e += TB_A)
        atomicAdd(&h[rows[e] >> 8], 1);
    __syncthreads();
    for (int i = threadIdx.x; i < NBUCK; i += TB_A) {
        int c = h[i];
        gb[i] = c ? atomicAdd(&gcur[i], c) : 0;
        h[i] = 0;
    }
    __syncthreads();
    for (int e = base + threadIdx.x; e < end; e += TB_A) {
        int r = rows[e];
        int b = r >> 8;
        int pos = gb[b] + atomicAdd(&h[b], 1);
        keys[pos] = ((r & 255) << 24) | e;  // e < 2^23, row-local in top byte
    }
}

// ---- Pass B: per-bucket row-grouping + stable (edge-idx) ordering -> cv, rs.
// (col,val) gathered from zip via e = key & 0xFFFFFF: ONE 64B line per edge. ----
__global__ __launch_bounds__(256) void k_build(const int* __restrict__ keys,
                                               const int2* __restrict__ zip,
                                               const int* __restrict__ bcnt,
                                               const int* __restrict__ bbase,
                                               int2* __restrict__ cv,
                                               int* __restrict__ rs) {
    __shared__ int cnt[256];
    __shared__ int start[256];
    __shared__ int cur[256];
    __shared__ int scanbuf[256];
    __shared__ int eKey[CAP];     // grouped keys (fast path)
    int tid = threadIdx.x;
    int b = blockIdx.x;
    int n = bcnt[b];
    int base = bbase[b];
    int rowbase = b << 8;
    cnt[tid] = 0;
    __syncthreads();
    // step 1: per-row-local histogram (LOGICAL shift: rl in [0,255])
    for (int i = tid; i < n; i += 256) {
        unsigned key = (unsigned)keys[base + i];
        atomicAdd(&cnt[key >> 24], 1);
    }
    __syncthreads();
    // exclusive scan of cnt -> start
    int v = cnt[tid];
    scanbuf[tid] = v;
    __syncthreads();
    for (int off = 1; off < 256; off <<= 1) {
        int t = 0;
        if (tid >= off) t = scanbuf[tid - off];
        __syncthreads();
        scanbuf[tid] += t;
        __syncthreads();
    }
    start[tid] = scanbuf[tid] - v;
    {
        int row = rowbase + tid;
        if (row < N_NODES) rs[row] = base + start[tid];
    }
    cur[tid] = 0;
    __syncthreads();
    if (n <= CAP) {
        // step 2: group keys by row into LDS (intra-row order arbitrary here)
        for (int i = tid; i < n; i += 256) {
            int key = keys[base + i];                   // L2-hot re-read
            int rl = (int)((unsigned)key >> 24);
            int p = start[rl] + atomicAdd(&cur[rl], 1);
            eKey[p] = key;
        }
        __syncthreads();
        // step 3: rank = #{same-row keys < mine} -> final slot; write cv ONCE.
        // Keys unique => bijection; same top byte within a row => signed cmp
        // orders by edge idx. (col,val) gathered from zip in one line.
        for (int p = tid; p < n; p += 256) {
            int k = eKey[p];
            int rl = (int)((unsigned)k >> 24);
            int s0 = start[rl];
            int s1 = s0 + cnt[rl];
            int rank = 0;
            int q = s0;
            for (; q + 4 <= s1; q += 4) {
                rank += (eKey[q]     < k);
                rank += (eKey[q + 1] < k);
                rank += (eKey[q + 2] < k);
                rank += (eKey[q + 3] < k);
            }
            for (; q < s1; ++q) rank += (eKey[q] < k);
            int e = k & 0x00FFFFFF;
            cv[base + s0 + rank] = zip[e];
        }
    } else {
        // overflow fallback (statistically unreachable, +11 sigma):
        // scatter keys into cv[].x, per-row insertion sort by key (global,
        // slow but correct), then rewrite each slot from zip via e.
        for (int i = tid; i < n; i += 256) {
            int key = keys[base + i];
            int rl = (int)((unsigned)key >> 24);
            int p = start[rl] + atomicAdd(&cur[rl], 1);
            cv[base + p] = make_int2(key, 0);
        }
        __syncthreads();
        int c = cnt[tid];
        if (c > 1) {
            int s0 = start[tid];
            int s1 = s0 + c;
            for (int i = s0 + 1; i < s1; ++i) {
                int2 kv = cv[base + i];
                int j = i - 1;
                while (j >= s0 && cv[base + j].x > kv.x) {
                    cv[base + j + 1] = cv[base + j];
                    --j;
                }
                cv[base + j + 1] = kv;
            }
        }
        __syncthreads();
        // each slot read exactly once by its own thread, then overwritten
        for (int i = tid; i < n; i += 256) {
            int e = cv[base + i].x & 0x00FFFFFF;
            cv[base + i] = zip[e];
        }
    }
}

// ---- per-row L2 norm of noise, numpy pairwise order (8 accumulators, n=64) ----
__global__ void k_norm(const float* __restrict__ nk, float* __restrict__ nrm) {
    __shared__ float tile[2][64 * 65];
    int wave = threadIdx.x >> 6;
    int lane = threadIdx.x & 63;
    int base = blockIdx.x * 128 + wave * 64;
    for (int rr = 0; rr < 64; ++rr) {
        int row = base + rr;
        float v = 0.f;
        if (row < N_NODES) v = nk[row * EMB + lane];
        tile[wave][rr * 65 + lane] = v;
    }
    __syncthreads();
    int row = base + lane;
    if (row < N_NODES) {
        const float* tp = &tile[wave][lane * 65];
        float rj[8];
        #pragma unroll
        for (int j = 0; j < 8; ++j) {
            float xj = tp[j];
            rj[j] = __fmul_rn(xj, xj);
        }
        #pragma unroll
        for (int i = 8; i < 64; i += 8) {
            #pragma unroll
            for (int j = 0; j < 8; ++j) {
                float xj = tp[i + j];
                rj[j] = __fadd_rn(rj[j], __fmul_rn(xj, xj));
            }
        }
        float s01 = __fadd_rn(rj[0], rj[1]);
        float s23 = __fadd_rn(rj[2], rj[3]);
        float s45 = __fadd_rn(rj[4], rj[5]);
        float s67 = __fadd_rn(rj[6], rj[7]);
        float ss = __fadd_rn(__fadd_rn(s01, s23), __fadd_rn(s45, s67));
        float nv = __fsqrt_rn(ss);
        nv = fmaxf(nv, 1e-12f);
        nrm[row] = nv;
    }
}

// ---- Fused SpMM + epilogue. One thread per (row, 4-dim group).
// 3-edge pipelined groups (R2 structure, <=64 VGPR). x gather selects
// {base, rebased col} in-kernel: layer 0 reads user/item directly
// (split=100000); layers 1-2 pass split=0 and xlo=xhi (select is inert,
// no OOB pointer ever formed).
// Epilogue: e4 = y + sign(y)*nk/nrm*0.1;
//   mode0: ego=e4, clF=e4            (accF deferred — mode1 reads clF)
//   mode1: ego=e4, accF=clF+e4
//   mode2: accF=(accF+e4)/3          (ego dead, not written)
__global__ __launch_bounds__(256) void k_fused(const int* __restrict__ rs,
                                               const int2* __restrict__ cv,
                                               const float* __restrict__ xlo,
                                               const float* __restrict__ xhi,
                                               int split,
                                               const float* __restrict__ nk,
                                               const float* __restrict__ nrm,
                                               float* __restrict__ ego,
                                               float* __restrict__ accF,
                                               float* __restrict__ clF,
                                               int mode) {
    int t = blockIdx.x * blockDim.x + threadIdx.x;
    if (t >= N_NODES * 16) return;
    int r = t >> 4;
    int c = (t & 15) << 2;
    int j0 = rs[r], j1 = rs[r + 1];
    float a0 = 0.f, a1 = 0.f, a2 = 0.f, a3 = 0.f;
    if (j0 < j1) {
        const int EMAX = N_EDGES - 1;
        // two-base gather: base and rebased column selected together
        #define XROW(col) (((col) < split ? xlo : xhi) + \
                           ((col) < split ? (col) : (col) - split) * EMB + c)
        int2 c0 = cv[j0];
        int2 c1 = cv[min(j0 + 1, EMAX)];
        int2 c2 = cv[min(j0 + 2, EMAX)];
        int2 n0 = cv[min(j0 + 3, EMAX)];
        int2 n1 = cv[min(j0 + 4, EMAX)];
        int2 n2 = cv[min(j0 + 5, EMAX)];
        int2 m0 = cv[min(j0 + 6, EMAX)];
        int2 m1 = cv[min(j0 + 7, EMAX)];
        int2 m2 = cv[min(j0 + 8, EMAX)];
        float4 x0 = *(const float4*)XROW(c0.x);
        float4 x1 = *(const float4*)XROW(c1.x);
        float4 x2 = *(const float4*)XROW(c2.x);
        for (int j = j0; j < j1; j += 3) {
            // x prefetch for next group (cv loaded 2 iterations ago)
            float4 y0 = *(const float4*)XROW(n0.x);
            float4 y1 = *(const float4*)XROW(n1.x);
            float4 y2 = *(const float4*)XROW(n2.x);
            // accumulate current group (predicate out-of-row edges to v=0;
            // a + (+/-0) is exact, so active-edge order/values unchanged)
            float v0 = __int_as_float(c0.y);
            float v1 = (j + 1 < j1) ? __int_as_float(c1.y) : 0.f;
            float v2 = (j + 2 < j1) ? __int_as_float(c2.y) : 0.f;
            a0 = __fadd_rn(a0, __fmul_rn(v0, x0.x));
            a1 = __fadd_rn(a1, __fmul_rn(v0, x0.y));
            a2 = __fadd_rn(a2, __fmul_rn(v0, x0.z));
            a3 = __fadd_rn(a3, __fmul_rn(v0, x0.w));
            a0 = __fadd_rn(a0, __fmul_rn(v1, x1.x));
            a1 = __fadd_rn(a1, __fmul_rn(v1, x1.y));
            a2 = __fadd_rn(a2, __fmul_rn(v1, x1.z));
            a3 = __fadd_rn(a3, __fmul_rn(v1, x1.w));
            a0 = __fadd_rn(a0, __fmul_rn(v2, x2.x));
            a1 = __fadd_rn(a1, __fmul_rn(v2, x2.y));
            a2 = __fadd_rn(a2, __fmul_rn(v2, x2.z));
            a3 = __fadd_rn(a3, __fmul_rn(v2, x2.w));
            // rotate pipeline
            c0 = n0; c1 = n1; c2 = n2;
            n0 = m0; n1 = m1; n2 = m2;
            x0 = y0; x1 = y1; x2 = y2;
            // streaming cv prefetch, 2 groups ahead of its x-gather
            m0 = cv[min(j + 9,  EMAX)];
            m1 = cv[min(j + 10, EMAX)];
            m2 = cv[min(j + 11, EMAX)];
        }
        #undef XROW
    }
    // ---- fused epilogue (identical math/order to the old k_epi) ----
    int idx = t << 2;
    float4 n4 = *(const float4*)(nk + idx);
    float nv = nrm[r];
    float4 e4;
    {
        float s, q;
        s = (a0 > 0.f) ? 1.f : ((a0 < 0.f) ? -1.f : 0.f);
        q = __fdiv_rn(n4.x, nv);
        e4.x = __fadd_rn(a0, __fmul_rn(__fmul_rn(s, q), 0.1f));
        s = (a1 > 0.f) ? 1.f : ((a1 < 0.f) ? -1.f : 0.f);
        q = __fdiv_rn(n4.y, nv);
        e4.y = __fadd_rn(a1, __fmul_rn(__fmul_rn(s, q), 0.1f));
        s = (a2 > 0.f) ? 1.f : ((a2 < 0.f) ? -1.f : 0.f);
        q = __fdiv_rn(n4.z, nv);
        e4.z = __fadd_rn(a2, __fmul_rn(__fmul_rn(s, q), 0.1f));
        s = (a3 > 0.f) ? 1.f : ((a3 < 0.f) ? -1.f : 0.f);
        q = __fdiv_rn(n4.w, nv);
        e4.w = __fadd_rn(a3, __fmul_rn(__fmul_rn(s, q), 0.1f));
    }
    if (mode == 0) {
        *(float4*)(ego + idx) = e4;
        *(float4*)(clF + idx) = e4;
    } else if (mode == 1) {
        *(float4*)(ego + idx) = e4;
        float4 a = *(const float4*)(clF + idx);   // == acc after layer 0
        a.x = __fadd_rn(a.x, e4.x);
        a.y = __fadd_rn(a.y, e4.y);
        a.z = __fadd_rn(a.z, e4.z);
        a.w = __fadd_rn(a.w, e4.w);
        *(float4*)(accF + idx) = a;
    } else {
        float4 a = *(const float4*)(accF + idx);
        float4 f;
        f.x = __fdiv_rn(__fadd_rn(a.x, e4.x), 3.0f);
        f.y = __fdiv_rn(__fadd_rn(a.y, e4.y), 3.0f);
        f.z = __fdiv_rn(__fadd_rn(a.z, e4.z), 3.0f);
        f.w = __fdiv_rn(__fadd_rn(a.w, e4.w), 3.0f);
        *(float4*)(accF + idx) = f;
    }
}

extern "C" void kernel_launch(void* const* d_in, const int* in_sizes, int n_in,
                              void* d_out, int out_size, void* d_ws, size_t ws_size,
                              hipStream_t stream) {
    if (ws_size < WS_NEED) return;

    const float* user_emb = (const float*)d_in[0];
    const float* item_emb = (const float*)d_in[1];
    const int*   adj_rows = (const int*)d_in[2];
    const int*   adj_cols = (const int*)d_in[3];
    const float* adj_vals = (const float*)d_in[4];
    const float* noise    = (const float*)d_in[5];

    char* ws = (char*)d_ws;
    float* bufA = (float*)(ws + BUFA_OFF);
    float* bufB = (float*)(ws + BUFB_OFF);
    int*   keys = (int*)(ws + BUFA_OFF);    // aliased: dead before bufA first write
    int2*  zip  = (int2*)(ws + BUFB_OFF);   // aliased: dead before bufB first write
    int2*  cv   = (int2*)(ws + CV_OFF);
    int*   rs   = (int*)(ws + RS_OFF);
    int*   bcnt = (int*)(ws + SMALL_OFF);
    int*   bbase= (int*)(ws + SMALL_OFF + 3200);
    int*   gcur = (int*)(ws + SMALL_OFF + 6400);
    float* nrm  = (float*)(ws + NRM_OFF);

    float* accF = (float*)d_out;
    float* clF  = (float*)d_out + (size_t)N_NODES * EMB;

    // ---- CSR build (keys/zip alias bufA/bufB: build completes before any
    //      fused layer writes ego into those buffers; single stream) ----
    hipMemsetAsync(bcnt, 0, NBUCK * sizeof(int), stream);
    const int NBLK = (N_EDGES + EPB - 1) / EPB;  // 391
    k_prep<<<NBLK, TB_A, 0, stream>>>(adj_rows, adj_cols, adj_vals, bcnt, zip);
    k_scan782<<<1, 1024, 0, stream>>>(bcnt, bbase, gcur, rs);
    k_bin<<<NBLK, TB_A, 0, stream>>>(adj_rows, gcur, keys);
    k_build<<<NBUCK, 256, 0, stream>>>(keys, zip, bcnt, bbase, cv, rs);

    // ---- 3 layers: norm(k) then fused spmm+epilogue(k) ----
    const int T16 = N_NODES * 16;
    for (int k = 0; k < 3; ++k) {
        const float* nkp = noise + (size_t)k * N_NODES * EMB;
        const float* xlo  = (k == 0) ? user_emb : ((k == 1) ? bufA : bufB);
        const float* xhi  = (k == 0) ? item_emb : ((k == 1) ? bufA : bufB);
        int split = (k == 0) ? USER_NUM : 0;
        float* ego_out = (k == 0) ? bufA : bufB;   // k==2 never writes ego
        k_norm<<<(N_NODES + 127) / 128, 128, 0, stream>>>(nkp, nrm);
        k_fused<<<(T16 + 255) / 256, 256, 0, stream>>>(rs, cv, xlo, xhi, split,
                                                       nkp, nrm, ego_out, accF,
                                                       clF, k);
    }
}